// Round 1
// baseline (4989.214 us; speedup 1.0000x reference)
//
#include <hip/hip_runtime.h>
#include <math.h>

// Problem constants (from reference): B=4, in_ch=128, out_ch=256, c4=64, S=64.
constexpr int Bn = 4;
constexpr int S  = 64;
constexpr int N  = 4096;  // S*S

#define DEV static __device__ __forceinline__

DEV void fma4(float4& a, float s, const float4 u) {
  a.x = fmaf(s, u.x, a.x); a.y = fmaf(s, u.y, a.y);
  a.z = fmaf(s, u.z, a.z); a.w = fmaf(s, u.w, a.w);
}

DEV void fma16(float acc[4][4], const float4 a, const float4 b) {
  acc[0][0] = fmaf(a.x, b.x, acc[0][0]); acc[0][1] = fmaf(a.x, b.y, acc[0][1]);
  acc[0][2] = fmaf(a.x, b.z, acc[0][2]); acc[0][3] = fmaf(a.x, b.w, acc[0][3]);
  acc[1][0] = fmaf(a.y, b.x, acc[1][0]); acc[1][1] = fmaf(a.y, b.y, acc[1][1]);
  acc[1][2] = fmaf(a.y, b.z, acc[1][2]); acc[1][3] = fmaf(a.y, b.w, acc[1][3]);
  acc[2][0] = fmaf(a.z, b.x, acc[2][0]); acc[2][1] = fmaf(a.z, b.y, acc[2][1]);
  acc[2][2] = fmaf(a.z, b.z, acc[2][2]); acc[2][3] = fmaf(a.z, b.w, acc[2][3]);
  acc[3][0] = fmaf(a.w, b.x, acc[3][0]); acc[3][1] = fmaf(a.w, b.y, acc[3][1]);
  acc[3][2] = fmaf(a.w, b.z, acc[3][2]); acc[3][3] = fmaf(a.w, b.w, acc[3][3]);
}

// ---------------- maxpool 2x2 into padded (halo=1) buffer ----------------
__global__ __launch_bounds__(256) void pool_kernel(const float* __restrict__ x,
                                                   float* __restrict__ P1) {
  int i = blockIdx.x * 256 + threadIdx.x;            // 4*128*64*64 = 2097152
  int xx = i & 63, yy = (i >> 6) & 63, cb = i >> 12; // cb = b*128+c
  const float* s = x + ((size_t)cb * 128 + 2 * yy) * 128 + 2 * xx;
  float m = fmaxf(fmaxf(s[0], s[1]), fmaxf(s[128], s[129]));
  P1[((size_t)cb * 66 + yy + 1) * 66 + xx + 1] = m;
}

// ---------------- generic 3x3 conv from a zero-padded input ----------------
// in: [b][Cin][Wp][Wp] padded with `halo`; out: [b][Cout][64][64] raw (pre-BN).
// padded coords for output (y,x), tap (ky,kx): row = y + ky*dil + (halo-dil).
__global__ __launch_bounds__(256) void conv3x3_kernel(
    const float* __restrict__ in, const float* __restrict__ w,
    const float* __restrict__ bias, float* __restrict__ out,
    int Cin, int dil, int halo) {
  __shared__ float wl[256 * 12];  // per-ci 9 taps padded to stride 12 (float4 reads)
  const int co = blockIdx.y, b = blockIdx.z, Cout = (int)gridDim.y;
  const int Wp = S + 2 * halo;
  for (int i = threadIdx.x; i < Cin * 9; i += 256) {
    int ci = i / 9, rr = i - ci * 9;
    wl[ci * 12 + (rr / 3) * 4 + (rr % 3)] = w[(size_t)(co * Cin + ci) * 9 + rr];
  }
  __syncthreads();
  const int tx = threadIdx.x & 15, ty = threadIdx.x >> 4;
  const int x0 = tx * 4, y = blockIdx.x * 16 + ty;
  const int hd = halo - dil;
  float a0, a1, a2, a3;
  a0 = a1 = a2 = a3 = bias ? bias[co] : 0.f;
  const float4* wl4 = (const float4*)wl;
  const float* pl = in + ((size_t)(b * Cin) * Wp + y + hd) * Wp + x0 + hd;
  const size_t pstride = (size_t)Wp * Wp;
  for (int ci = 0; ci < Cin; ci++, pl += pstride) {
#pragma unroll
    for (int ky = 0; ky < 3; ky++) {
      const float* rw = pl + ky * dil * Wp;
      float4 u0 = *(const float4*)(rw);
      float4 u1 = *(const float4*)(rw + dil);
      float4 u2 = *(const float4*)(rw + 2 * dil);
      float4 wv = wl4[ci * 3 + ky];
      a0 = fmaf(wv.x, u0.x, fmaf(wv.y, u1.x, fmaf(wv.z, u2.x, a0)));
      a1 = fmaf(wv.x, u0.y, fmaf(wv.y, u1.y, fmaf(wv.z, u2.y, a1)));
      a2 = fmaf(wv.x, u0.z, fmaf(wv.y, u1.z, fmaf(wv.z, u2.z, a2)));
      a3 = fmaf(wv.x, u0.w, fmaf(wv.y, u1.w, fmaf(wv.z, u2.w, a3)));
    }
  }
  *(float4*)(out + ((size_t)(b * Cout + co)) * N + y * S + x0) =
      make_float4(a0, a1, a2, a3);
}

// ---------------- BN training-mode stats -> per-channel scale/shift ----------------
__global__ __launch_bounds__(256) void bn_stats_kernel(
    const float* __restrict__ t, const float* __restrict__ gamma,
    const float* __restrict__ beta, float* __restrict__ ss, int C) {
  const int c = blockIdx.x;
  float s = 0.f, s2 = 0.f;
  for (int b = 0; b < Bn; b++) {
    const float* p = t + ((size_t)(b * C + c)) * N;
    for (int i = threadIdx.x; i < N; i += 256) {
      float v = p[i];
      s += v; s2 = fmaf(v, v, s2);
    }
  }
  for (int off = 32; off; off >>= 1) {
    s += __shfl_down(s, off, 64);
    s2 += __shfl_down(s2, off, 64);
  }
  __shared__ float rs[4], rs2[4];
  const int wid = threadIdx.x >> 6, lane = threadIdx.x & 63;
  if (lane == 0) { rs[wid] = s; rs2[wid] = s2; }
  __syncthreads();
  if (threadIdx.x == 0) {
    float S1 = rs[0] + rs[1] + rs[2] + rs[3];
    float S2 = rs2[0] + rs2[1] + rs2[2] + rs2[3];
    const float cnt = (float)(Bn * N);
    float mean = S1 / cnt;
    float var = S2 / cnt - mean * mean;  // biased (ddof=0), matches jnp.var
    float sc = gamma[c] * rsqrtf(var + 1e-5f);
    ss[2 * c] = sc;
    ss[2 * c + 1] = beta[c] - mean * sc;
  }
}

// normalize+ReLU, writing into a zero-padded buffer (halo)
__global__ __launch_bounds__(256) void bn_norm_pad_kernel(
    const float* __restrict__ t, const float* __restrict__ ss,
    float* __restrict__ outp, int Cmask, int halo) {
  int i = blockIdx.x * 256 + threadIdx.x;
  int xx = i & 63, yy = (i >> 6) & 63, cn = i >> 12;  // cn = b*C+c
  int c = cn & Cmask;
  float v = fmaxf(fmaf(t[i], ss[2 * c], ss[2 * c + 1]), 0.f);
  int Wp = S + 2 * halo;
  outp[((size_t)cn * Wp + yy + halo) * Wp + xx + halo] = v;
}

// normalize+ReLU in place (ASPP branch outputs)
__global__ __launch_bounds__(256) void bn_norm_kernel(
    float* __restrict__ t, const float* __restrict__ ss, int Cmask) {
  int i = blockIdx.x * 256 + threadIdx.x;
  int c = (i >> 12) & Cmask;
  t[i] = fmaxf(fmaf(t[i], ss[2 * c], ss[2 * c + 1]), 0.f);
}

// ---------------- ASPP branch 1: 1x1 conv 256->64 reading padded P3 ----------------
// grid (16 ntile, 4 dgroup, 4 b); block: 16 d x 256 n (4d x 4n per thread)
__global__ __launch_bounds__(256) void aspp1_kernel(
    const float* __restrict__ P3, const float* __restrict__ w,
    float* __restrict__ out) {
  __shared__ float wl[256 * 16];  // wl[ci*16 + dlocal]
  const int b = blockIdx.z, dg = blockIdx.y, nt = blockIdx.x;
  const int d0b = dg * 16;
  for (int i = threadIdx.x; i < 256 * 16; i += 256)
    wl[i] = w[(size_t)(d0b + (i & 15)) * 256 + (i >> 4)];
  __syncthreads();
  const int tn = threadIdx.x & 63, td = threadIdx.x >> 6;
  const int n0 = nt * 256 + tn * 4;
  const int yy = n0 >> 6, xx = n0 & 63;
  float4 acc[4] = {};
  const float* base = P3 + ((size_t)(b * 256) * 82 + 9 + yy) * 82 + 9 + xx;
  for (int ci = 0; ci < 256; ci++) {
    float4 u = *(const float4*)(base + (size_t)ci * 82 * 82);
    float4 wv = *(const float4*)(wl + ci * 16 + td * 4);
    fma4(acc[0], wv.x, u); fma4(acc[1], wv.y, u);
    fma4(acc[2], wv.z, u); fma4(acc[3], wv.w, u);
  }
#pragma unroll
  for (int j = 0; j < 4; j++)
    *(float4*)(out + ((size_t)(b * 64 + d0b + td * 4 + j)) * N + n0) = acc[j];
}

// ---------------- q/k/v 1x1 convs (64->64) for all 16 (branch,b) slabs ----------------
// grid (16 ntile, 12 = proj*4+dgroup, 16 = branch*4+b)
__global__ __launch_bounds__(256) void qkv_kernel(
    const float* __restrict__ br,
    const float* __restrict__ wq, const float* __restrict__ bq,
    const float* __restrict__ wk, const float* __restrict__ bk,
    const float* __restrict__ wv, const float* __restrict__ bv,
    float* __restrict__ qkv) {
  const int bb = blockIdx.z;
  const int p = blockIdx.y >> 2, dg = blockIdx.y & 3;
  const float* w  = p == 0 ? wq : (p == 1 ? wk : wv);
  const float* bi = p == 0 ? bq : (p == 1 ? bk : bv);
  __shared__ float wl[64 * 16];
  const int d0b = dg * 16;
  for (int i = threadIdx.x; i < 64 * 16; i += 256)
    wl[i] = w[(size_t)(d0b + (i & 15)) * 64 + (i >> 4)];
  __syncthreads();
  const int tn = threadIdx.x & 63, td = threadIdx.x >> 6;
  const int n0 = blockIdx.x * 256 + tn * 4;
  const int d0 = d0b + td * 4;
  const float* inb = br + (size_t)bb * 64 * N;
  float4 acc[4];
#pragma unroll
  for (int j = 0; j < 4; j++) {
    float bvv = bi[d0 + j];
    acc[j] = make_float4(bvv, bvv, bvv, bvv);
  }
  for (int ci = 0; ci < 64; ci++) {
    float4 u = *(const float4*)(inb + (size_t)ci * N + n0);
    float4 wv4 = *(const float4*)(wl + ci * 16 + td * 4);
    fma4(acc[0], wv4.x, u); fma4(acc[1], wv4.y, u);
    fma4(acc[2], wv4.z, u); fma4(acc[3], wv4.w, u);
  }
  float* o = qkv + ((size_t)(bb * 3 + p) * 64) * N;
#pragma unroll
  for (int j = 0; j < 4; j++)
    *(float4*)(o + (size_t)(d0 + j) * N + n0) = acc[j];
}

// ---------------- pos[d][n] = rel_w[d][n>>6] + rel_h[d][n&63] ----------------
__global__ __launch_bounds__(256) void pos_kernel(
    const float* __restrict__ rel_h, const float* __restrict__ rel_w,
    float* __restrict__ pos) {
  int i = blockIdx.x * 256 + threadIdx.x;  // 64*4096
  int n = i & (N - 1), d = i >> 12;
  pos[i] = rel_w[d * 64 + (n >> 6)] + rel_h[d * 64 + (n & 63)];
}

// ---------------- logits GEMM: L[m][c] = sum_dd A[dd][m]*B[dd][c], K=128 ----------------
// A rows: [q ; pos], B rows: [k ; q]. 64x64 tile, 4x4 micro, K-chunks of 32.
__global__ __launch_bounds__(256) void lgemm_kernel(
    const float* __restrict__ q, const float* __restrict__ k,
    const float* __restrict__ pos, float* __restrict__ Lb) {
  __shared__ float As[32][64];
  __shared__ float Bs[32][64];
  const int m0 = blockIdx.x * 64, c0 = blockIdx.y * 64;
  const int tx = threadIdx.x & 15, ty = threadIdx.x >> 4;
  float acc[4][4] = {};
  for (int k0 = 0; k0 < 128; k0 += 32) {
    __syncthreads();
#pragma unroll
    for (int j = 0; j < 2; j++) {
      int f = threadIdx.x + j * 256;
      int rr = f >> 4, col = (f & 15) * 4;
      int dd = k0 + rr;
      const float* arow = dd < 64 ? q + (size_t)dd * N : pos + (size_t)(dd - 64) * N;
      const float* brow = dd < 64 ? k + (size_t)dd * N : q + (size_t)(dd - 64) * N;
      *(float4*)&As[rr][col] = *(const float4*)(arow + m0 + col);
      *(float4*)&Bs[rr][col] = *(const float4*)(brow + c0 + col);
    }
    __syncthreads();
#pragma unroll
    for (int kk = 0; kk < 32; kk++) {
      float4 a = *(const float4*)&As[kk][ty * 4];
      float4 bv = *(const float4*)&Bs[kk][tx * 4];
      fma16(acc, a, bv);
    }
  }
#pragma unroll
  for (int i = 0; i < 4; i++)
    *(float4*)(Lb + (size_t)(m0 + ty * 4 + i) * N + c0 + tx * 4) =
        make_float4(acc[i][0], acc[i][1], acc[i][2], acc[i][3]);
}

// ---------------- per-row max and 1/sum(exp) ----------------
__global__ __launch_bounds__(256) void rowstat_kernel(
    const float* __restrict__ Lb, float* __restrict__ rmx, float* __restrict__ rinv) {
  const int m = blockIdx.x;
  const float4* row = (const float4*)(Lb + (size_t)m * N);
  float4 v[4];
  float mx = -3.0e38f;
#pragma unroll
  for (int i = 0; i < 4; i++) {
    v[i] = row[threadIdx.x + i * 256];
    mx = fmaxf(mx, fmaxf(fmaxf(v[i].x, v[i].y), fmaxf(v[i].z, v[i].w)));
  }
  for (int off = 32; off; off >>= 1) mx = fmaxf(mx, __shfl_down(mx, off, 64));
  __shared__ float sm[4], ssum[4];
  const int wid = threadIdx.x >> 6, lane = threadIdx.x & 63;
  if (lane == 0) sm[wid] = mx;
  __syncthreads();
  mx = fmaxf(fmaxf(sm[0], sm[1]), fmaxf(sm[2], sm[3]));
  float s = 0.f;
#pragma unroll
  for (int i = 0; i < 4; i++)
    s += __expf(v[i].x - mx) + __expf(v[i].y - mx) + __expf(v[i].z - mx) +
         __expf(v[i].w - mx);
  for (int off = 32; off; off >>= 1) s += __shfl_down(s, off, 64);
  if (lane == 0) ssum[wid] = s;
  __syncthreads();
  if (threadIdx.x == 0) {
    rmx[m] = mx;
    rinv[m] = 1.0f / (ssum[0] + ssum[1] + ssum[2] + ssum[3]);
  }
}

// ---------------- O GEMM: part[ks][d][m] = sum_{c in split} exp(L[m][c]-mx[m])*V[d][c] * rinv[m]
// grid (64 mtiles, 8 ksplits); block: 64m x 64d, 4x4 micro, c-chunks of 32.
__global__ __launch_bounds__(256) void ogemm_kernel(
    const float* __restrict__ Lb, const float* __restrict__ V,
    const float* __restrict__ rmx, const float* __restrict__ rinv,
    float* __restrict__ part) {
  __shared__ float Pt[32][68];  // [c][m], +4 pad to tame write conflicts
  __shared__ float Vt[32][68];  // [c][d]
  const int m0 = blockIdx.x * 64;
  const int c_base = blockIdx.y * 512;
  const int tx = threadIdx.x & 15, ty = threadIdx.x >> 4;
  float acc[4][4] = {};
  for (int cc = 0; cc < 512; cc += 32) {
    const int c0 = c_base + cc;
    __syncthreads();
#pragma unroll
    for (int j = 0; j < 2; j++) {
      int f = threadIdx.x + j * 256;
      int rl = f >> 3, cf = (f & 7) * 4;
      float4 u = *(const float4*)(Lb + (size_t)(m0 + rl) * N + c0 + cf);
      float mxv = rmx[m0 + rl];
      Pt[cf + 0][rl] = __expf(u.x - mxv);
      Pt[cf + 1][rl] = __expf(u.y - mxv);
      Pt[cf + 2][rl] = __expf(u.z - mxv);
      Pt[cf + 3][rl] = __expf(u.w - mxv);
      float4 w4 = *(const float4*)(V + (size_t)rl * N + c0 + cf);
      Vt[cf + 0][rl] = w4.x;
      Vt[cf + 1][rl] = w4.y;
      Vt[cf + 2][rl] = w4.z;
      Vt[cf + 3][rl] = w4.w;
    }
    __syncthreads();
#pragma unroll
    for (int kk = 0; kk < 32; kk++) {
      float4 a = *(const float4*)&Pt[kk][ty * 4];   // 4 m's
      float4 bv = *(const float4*)&Vt[kk][tx * 4];  // 4 d's
      fma16(acc, a, bv);                            // acc[m][d]
    }
  }
  const float r0 = rinv[m0 + ty * 4 + 0], r1 = rinv[m0 + ty * 4 + 1],
              r2 = rinv[m0 + ty * 4 + 2], r3 = rinv[m0 + ty * 4 + 3];
  float* pb = part + (size_t)blockIdx.y * (64 * N);
#pragma unroll
  for (int j = 0; j < 4; j++) {
    int d = tx * 4 + j;
    *(float4*)(pb + (size_t)d * N + m0 + ty * 4) =
        make_float4(acc[0][j] * r0, acc[1][j] * r1, acc[2][j] * r2, acc[3][j] * r3);
  }
}

// ---------------- reduce 8 split partials -> d_out slab ----------------
__global__ __launch_bounds__(256) void reduce_kernel(
    const float* __restrict__ part, float* __restrict__ outp) {
  int i = blockIdx.x * 256 + threadIdx.x;  // over 64*4096/4 = 65536 float4s
  const float4* p4 = (const float4*)part;
  float4 s = p4[i];
  for (int kS = 1; kS < 8; kS++) {
    float4 u = p4[i + kS * 65536];
    s.x += u.x; s.y += u.y; s.z += u.z; s.w += u.w;
  }
  ((float4*)outp)[i] = s;
}

extern "C" void kernel_launch(void* const* d_in, const int* in_sizes, int n_in,
                              void* d_out, int out_size, void* d_ws, size_t ws_size,
                              hipStream_t stream) {
  const float* x      = (const float*)d_in[0];
  const float* dc_w1  = (const float*)d_in[1];
  const float* dc_b1  = (const float*)d_in[2];
  const float* dc_g1  = (const float*)d_in[3];
  const float* dc_be1 = (const float*)d_in[4];
  const float* dc_w2  = (const float*)d_in[5];
  const float* dc_b2  = (const float*)d_in[6];
  const float* dc_g2  = (const float*)d_in[7];
  const float* dc_be2 = (const float*)d_in[8];
  const float* aspp_w[4] = {(const float*)d_in[9],  (const float*)d_in[12],
                            (const float*)d_in[15], (const float*)d_in[18]};
  const float* aspp_g[4] = {(const float*)d_in[10], (const float*)d_in[13],
                            (const float*)d_in[16], (const float*)d_in[19]};
  const float* aspp_b[4] = {(const float*)d_in[11], (const float*)d_in[14],
                            (const float*)d_in[17], (const float*)d_in[20]};
  const float* wq = (const float*)d_in[21];
  const float* bq = (const float*)d_in[22];
  const float* wk = (const float*)d_in[23];
  const float* bk = (const float*)d_in[24];
  const float* wv = (const float*)d_in[25];
  const float* bv = (const float*)d_in[26];
  const float* rel_h = (const float*)d_in[27];
  const float* rel_w = (const float*)d_in[28];
  float* out = (float*)d_out;

  // workspace layout (floats); total ~53.7M floats ~= 215 MB
  float* ws = (float*)d_ws;
  size_t off = 0;
  auto alloc = [&](size_t nf) { float* p = ws + off; off += nf; return p; };
  float* P1   = alloc((size_t)4 * 128 * 66 * 66);  // pooled, padded halo=1
  float* P2   = alloc((size_t)4 * 256 * 66 * 66);  // h1, padded halo=1
  float* P3   = alloc((size_t)4 * 256 * 82 * 82);  // h2, padded halo=9
  float* t1   = alloc((size_t)4 * 256 * N);        // raw conv out (reused)
  float* br   = alloc((size_t)4 * 4 * 64 * N);     // [branch][b][d][n]
  float* qkv  = alloc((size_t)16 * 3 * 64 * N);    // [br*4+b][{q,k,v}][d][n]
  float* pos  = alloc((size_t)64 * N);
  float* Lbuf = alloc((size_t)N * N);              // 64 MB logits, reused per pair
  float* part = alloc((size_t)8 * 64 * N);         // split-K partials
  float* rmx  = alloc(N);
  float* rinv = alloc(N);
  float* st1  = alloc(512);
  float* st2  = alloc(512);
  float* sta  = alloc(4 * 128);

  // zero halos (interiors are overwritten)
  hipMemsetAsync(P1, 0, (size_t)4 * 128 * 66 * 66 * 4, stream);
  hipMemsetAsync(P2, 0, (size_t)4 * 256 * 66 * 66 * 4, stream);
  hipMemsetAsync(P3, 0, (size_t)4 * 256 * 82 * 82 * 4, stream);

  pool_kernel<<<8192, 256, 0, stream>>>(x, P1);

  // double_conv
  conv3x3_kernel<<<dim3(4, 256, 4), 256, 0, stream>>>(P1, dc_w1, dc_b1, t1, 128, 1, 1);
  bn_stats_kernel<<<256, 256, 0, stream>>>(t1, dc_g1, dc_be1, st1, 256);
  bn_norm_pad_kernel<<<16384, 256, 0, stream>>>(t1, st1, P2, 255, 1);
  conv3x3_kernel<<<dim3(4, 256, 4), 256, 0, stream>>>(P2, dc_w2, dc_b2, t1, 256, 1, 1);
  bn_stats_kernel<<<256, 256, 0, stream>>>(t1, dc_g2, dc_be2, st2, 256);
  bn_norm_pad_kernel<<<16384, 256, 0, stream>>>(t1, st2, P3, 255, 9);

  // ASPP branches
  aspp1_kernel<<<dim3(16, 4, 4), 256, 0, stream>>>(P3, aspp_w[0], br);
  const int dils[3] = {3, 6, 9};
  for (int kbr = 1; kbr < 4; kbr++)
    conv3x3_kernel<<<dim3(4, 64, 4), 256, 0, stream>>>(
        P3, aspp_w[kbr], nullptr, br + (size_t)kbr * 1048576, 256, dils[kbr - 1], 9);
  for (int kbr = 0; kbr < 4; kbr++) {
    bn_stats_kernel<<<64, 256, 0, stream>>>(br + (size_t)kbr * 1048576,
                                            aspp_g[kbr], aspp_b[kbr],
                                            sta + kbr * 128, 64);
    bn_norm_kernel<<<4096, 256, 0, stream>>>(br + (size_t)kbr * 1048576,
                                             sta + kbr * 128, 63);
  }

  // projections + positional matrix
  qkv_kernel<<<dim3(16, 12, 16), 256, 0, stream>>>(br, wq, bq, wk, bk, wv, bv, qkv);
  pos_kernel<<<1024, 256, 0, stream>>>(rel_h, rel_w, pos);

  // attention per (branch, b), logits buffer reused sequentially (L3-resident)
  for (int bb = 0; bb < 16; bb++) {
    const int kbr = bb >> 2, b = bb & 3;
    const float* qp = qkv + ((size_t)(bb * 3 + 0) * 64) * N;
    const float* kp = qkv + ((size_t)(bb * 3 + 1) * 64) * N;
    const float* vp = qkv + ((size_t)(bb * 3 + 2) * 64) * N;
    lgemm_kernel<<<dim3(64, 64), 256, 0, stream>>>(qp, kp, pos, Lbuf);
    rowstat_kernel<<<4096, 256, 0, stream>>>(Lbuf, rmx, rinv);
    ogemm_kernel<<<dim3(64, 8), 256, 0, stream>>>(Lbuf, vp, rmx, rinv, part);
    reduce_kernel<<<256, 256, 0, stream>>>(
        part, out + ((size_t)b * 256 + (size_t)kbr * 64) * N);
  }
}

// Round 2
// 2203.456 us; speedup vs baseline: 2.2643x; 2.2643x over previous
//
#include <hip/hip_runtime.h>
#include <math.h>

constexpr int Bn = 4;
constexpr int S  = 64;
constexpr int N  = 4096;  // S*S

#define DEV static __device__ __forceinline__

typedef __attribute__((ext_vector_type(8))) short bf16x8;
typedef __attribute__((ext_vector_type(4))) float f32x4;

DEV unsigned short bfc(float x) {  // f32 -> bf16 RNE
  unsigned u = __float_as_uint(x);
  unsigned r = (u + 0x7FFFu + ((u >> 16) & 1u)) >> 16;
  return (unsigned short)r;
}

DEV void fma4(float4& a, float s, const float4 u) {
  a.x = fmaf(s, u.x, a.x); a.y = fmaf(s, u.y, a.y);
  a.z = fmaf(s, u.z, a.z); a.w = fmaf(s, u.w, a.w);
}

// ---------------- maxpool 2x2 into padded (halo=1) buffer ----------------
__global__ __launch_bounds__(256) void pool_kernel(const float* __restrict__ x,
                                                   float* __restrict__ P1) {
  int i = blockIdx.x * 256 + threadIdx.x;
  int xx = i & 63, yy = (i >> 6) & 63, cb = i >> 12;
  const float* s = x + ((size_t)cb * 128 + 2 * yy) * 128 + 2 * xx;
  float m = fmaxf(fmaxf(s[0], s[1]), fmaxf(s[128], s[129]));
  P1[((size_t)cb * 66 + yy + 1) * 66 + xx + 1] = m;
}

// ---------------- 3x3 conv, COG output channels per thread ----------------
// Weights read through wave-uniform indices (scalar cache); inputs reused
// across COG channels: FMA:VMEM ratio = 16*COG : 9 per ci.
template <int COG>
__global__ __launch_bounds__(256) void conv3x3_kernel(
    const float* __restrict__ in, const float* __restrict__ w,
    const float* __restrict__ bias, float* __restrict__ out,
    int Cin, int dil, int halo, int Cout) {
  const int b = blockIdx.z, co0 = blockIdx.y * COG;
  const int Wp = S + 2 * halo;
  const int tx = threadIdx.x & 15, ty = threadIdx.x >> 4;
  const int x0 = tx * 4, y = blockIdx.x * 16 + ty;
  const int hd = halo - dil;
  float4 acc[COG];
#pragma unroll
  for (int cl = 0; cl < COG; cl++) {
    float bv = bias ? bias[co0 + cl] : 0.f;
    acc[cl] = make_float4(bv, bv, bv, bv);
  }
  const float* base = in + ((size_t)(b * Cin) * Wp + y + hd) * Wp + x0 + hd;
  const size_t pstride = (size_t)Wp * Wp;
  for (int ci = 0; ci < Cin; ci++) {
    const float* pl = base + (size_t)ci * pstride;
#pragma unroll
    for (int ky = 0; ky < 3; ky++) {
      const float* rw = pl + ky * dil * Wp;
      float4 u0 = *(const float4*)(rw);
      float4 u1 = *(const float4*)(rw + dil);
      float4 u2 = *(const float4*)(rw + 2 * dil);
#pragma unroll
      for (int cl = 0; cl < COG; cl++) {
        const float* wc = w + ((size_t)(co0 + cl) * Cin + ci) * 9 + ky * 3;
        float w0 = wc[0], w1 = wc[1], w2 = wc[2];
        acc[cl].x = fmaf(w0, u0.x, fmaf(w1, u1.x, fmaf(w2, u2.x, acc[cl].x)));
        acc[cl].y = fmaf(w0, u0.y, fmaf(w1, u1.y, fmaf(w2, u2.y, acc[cl].y)));
        acc[cl].z = fmaf(w0, u0.z, fmaf(w1, u1.z, fmaf(w2, u2.z, acc[cl].z)));
        acc[cl].w = fmaf(w0, u0.w, fmaf(w1, u1.w, fmaf(w2, u2.w, acc[cl].w)));
      }
    }
  }
#pragma unroll
  for (int cl = 0; cl < COG; cl++)
    *(float4*)(out + ((size_t)(b * Cout + co0 + cl)) * N + y * S + x0) = acc[cl];
}

// ---------------- BN training-mode stats -> per-channel scale/shift ----------------
__global__ __launch_bounds__(256) void bn_stats_kernel(
    const float* __restrict__ t, const float* __restrict__ gamma,
    const float* __restrict__ beta, float* __restrict__ ss, int C) {
  const int c = blockIdx.x;
  float s = 0.f, s2 = 0.f;
  for (int b = 0; b < Bn; b++) {
    const float* p = t + ((size_t)(b * C + c)) * N;
    for (int i = threadIdx.x; i < N; i += 256) {
      float v = p[i];
      s += v; s2 = fmaf(v, v, s2);
    }
  }
  for (int off = 32; off; off >>= 1) {
    s += __shfl_down(s, off, 64);
    s2 += __shfl_down(s2, off, 64);
  }
  __shared__ float rs[4], rs2[4];
  const int wid = threadIdx.x >> 6, lane = threadIdx.x & 63;
  if (lane == 0) { rs[wid] = s; rs2[wid] = s2; }
  __syncthreads();
  if (threadIdx.x == 0) {
    float S1 = rs[0] + rs[1] + rs[2] + rs[3];
    float S2 = rs2[0] + rs2[1] + rs2[2] + rs2[3];
    const float cnt = (float)(Bn * N);
    float mean = S1 / cnt;
    float var = S2 / cnt - mean * mean;
    float sc = gamma[c] * rsqrtf(var + 1e-5f);
    ss[2 * c] = sc;
    ss[2 * c + 1] = beta[c] - mean * sc;
  }
}

__global__ __launch_bounds__(256) void bn_norm_pad_kernel(
    const float* __restrict__ t, const float* __restrict__ ss,
    float* __restrict__ outp, int Cmask, int halo) {
  int i = blockIdx.x * 256 + threadIdx.x;
  int xx = i & 63, yy = (i >> 6) & 63, cn = i >> 12;
  int c = cn & Cmask;
  float v = fmaxf(fmaf(t[i], ss[2 * c], ss[2 * c + 1]), 0.f);
  int Wp = S + 2 * halo;
  outp[((size_t)cn * Wp + yy + halo) * Wp + xx + halo] = v;
}

__global__ __launch_bounds__(256) void bn_norm_kernel(
    float* __restrict__ t, const float* __restrict__ ss, int Cmask) {
  int i = blockIdx.x * 256 + threadIdx.x;
  int c = (i >> 12) & Cmask;
  t[i] = fmaxf(fmaf(t[i], ss[2 * c], ss[2 * c + 1]), 0.f);
}

// ---------------- ASPP branch 1: 1x1 conv 256->64 ----------------
__global__ __launch_bounds__(256) void aspp1_kernel(
    const float* __restrict__ P3, const float* __restrict__ w,
    float* __restrict__ out) {
  __shared__ float wl[256 * 16];
  const int b = blockIdx.z, dg = blockIdx.y, nt = blockIdx.x;
  const int d0b = dg * 16;
  for (int i = threadIdx.x; i < 256 * 16; i += 256)
    wl[i] = w[(size_t)(d0b + (i & 15)) * 256 + (i >> 4)];
  __syncthreads();
  const int tn = threadIdx.x & 63, td = threadIdx.x >> 6;
  const int n0 = nt * 256 + tn * 4;
  const int yy = n0 >> 6, xx = n0 & 63;
  float4 acc[4] = {};
  const float* base = P3 + ((size_t)(b * 256) * 82 + 9 + yy) * 82 + 9 + xx;
  for (int ci = 0; ci < 256; ci++) {
    float4 u = *(const float4*)(base + (size_t)ci * 82 * 82);
    float4 wv = *(const float4*)(wl + ci * 16 + td * 4);
    fma4(acc[0], wv.x, u); fma4(acc[1], wv.y, u);
    fma4(acc[2], wv.z, u); fma4(acc[3], wv.w, u);
  }
#pragma unroll
  for (int j = 0; j < 4; j++)
    *(float4*)(out + ((size_t)(b * 64 + d0b + td * 4 + j)) * N + n0) = acc[j];
}

// ---------------- q/k/v 1x1 convs -> bf16 MFMA-layout buffers ----------------
// q,k written transposed [n][d] (A/B frag rows); v written [d][n].
__global__ __launch_bounds__(256) void qkv_kernel(
    const float* __restrict__ br,
    const float* __restrict__ wq, const float* __restrict__ bq,
    const float* __restrict__ wk, const float* __restrict__ bk,
    const float* __restrict__ wv, const float* __restrict__ bvb,
    unsigned short* __restrict__ qTo, unsigned short* __restrict__ kTo,
    unsigned short* __restrict__ vbo) {
  const int bb = blockIdx.z;
  const int p = blockIdx.y >> 2, dg = blockIdx.y & 3;
  const float* w  = p == 0 ? wq : (p == 1 ? wk : wv);
  const float* bi = p == 0 ? bq : (p == 1 ? bk : bvb);
  __shared__ float wl[64 * 16];
  const int d0b = dg * 16;
  for (int i = threadIdx.x; i < 64 * 16; i += 256)
    wl[i] = w[(size_t)(d0b + (i & 15)) * 64 + (i >> 4)];
  __syncthreads();
  const int tn = threadIdx.x & 63, td = threadIdx.x >> 6;
  const int n0 = blockIdx.x * 256 + tn * 4;
  const int d0 = d0b + td * 4;
  const float* inb = br + (size_t)bb * 64 * N;
  float4 acc[4];
#pragma unroll
  for (int j = 0; j < 4; j++) {
    float bvv = bi[d0 + j];
    acc[j] = make_float4(bvv, bvv, bvv, bvv);
  }
  for (int ci = 0; ci < 64; ci++) {
    float4 u = *(const float4*)(inb + (size_t)ci * N + n0);
    float4 wv4 = *(const float4*)(wl + ci * 16 + td * 4);
    fma4(acc[0], wv4.x, u); fma4(acc[1], wv4.y, u);
    fma4(acc[2], wv4.z, u); fma4(acc[3], wv4.w, u);
  }
  const size_t slab = (size_t)bb * N * 64;
  if (p < 2) {
    unsigned short* o = (p == 0 ? qTo : kTo) + slab;
#pragma unroll
    for (int nn = 0; nn < 4; nn++) {
      ushort4 pk;
      pk.x = bfc(((const float*)&acc[0])[nn]);
      pk.y = bfc(((const float*)&acc[1])[nn]);
      pk.z = bfc(((const float*)&acc[2])[nn]);
      pk.w = bfc(((const float*)&acc[3])[nn]);
      *(ushort4*)(o + (size_t)(n0 + tn * 0 + tn * 4 - tn * 4 + n0 * 0 + (n0 + nn)) * 0 +
                  (size_t)(n0 + nn) * 64 + d0) = pk;
    }
  } else {
    unsigned short* o = vbo + slab;
#pragma unroll
    for (int j = 0; j < 4; j++) {
      ushort4 pk;
      pk.x = bfc(acc[j].x); pk.y = bfc(acc[j].y);
      pk.z = bfc(acc[j].z); pk.w = bfc(acc[j].w);
      *(ushort4*)(o + (size_t)(d0 + j) * N + n0) = pk;
    }
  }
}

// ---------------- posT[n][d] = rel_w[d][h] + rel_h[d][w], bf16 ----------------
__global__ __launch_bounds__(256) void posT_kernel(
    const float* __restrict__ rel_h, const float* __restrict__ rel_w,
    unsigned short* __restrict__ posT) {
  int i = blockIdx.x * 256 + threadIdx.x;  // 65536
  int n = i >> 4, dq = (i & 15) * 4;
  int h = n >> 6, wc = n & 63;
  ushort4 pk;
  pk.x = bfc(rel_w[(dq + 0) * 64 + h] + rel_h[(dq + 0) * 64 + wc]);
  pk.y = bfc(rel_w[(dq + 1) * 64 + h] + rel_h[(dq + 1) * 64 + wc]);
  pk.z = bfc(rel_w[(dq + 2) * 64 + h] + rel_h[(dq + 2) * 64 + wc]);
  pk.w = bfc(rel_w[(dq + 3) * 64 + h] + rel_h[(dq + 3) * 64 + wc]);
  *(ushort4*)(posT + (size_t)n * 64 + dq) = pk;
}

// ---------------- logits: L[m][c] = sum_k [q;pos][m][k]*[k;q][c][k] ----------------
// MFMA 16x16x32 bf16, register-direct frag loads (no LDS). Block=128x128, K=128.
__global__ __launch_bounds__(256) void lgemm_kernel(
    const unsigned short* __restrict__ qT, const unsigned short* __restrict__ kT,
    const unsigned short* __restrict__ posT, float* __restrict__ Lb) {
  const int w = threadIdx.x >> 6, lane = threadIdx.x & 63;
  const int ln = lane & 15, quad = lane >> 4;
  const int m0 = blockIdx.x * 128 + (w & 1) * 64;
  const int c0 = blockIdx.y * 128 + (w >> 1) * 64;
  f32x4 acc[4][4];
#pragma unroll
  for (int i = 0; i < 4; i++)
#pragma unroll
    for (int j = 0; j < 4; j++) acc[i][j] = (f32x4)(0.f);
#pragma unroll
  for (int s = 0; s < 4; s++) {
    const int koff = (s & 1) * 32 + quad * 8;
    const unsigned short* ab = (s < 2) ? qT : posT;
    const unsigned short* bbp = (s < 2) ? kT : qT;
    bf16x8 a[4], bfr[4];
#pragma unroll
    for (int i = 0; i < 4; i++)
      a[i] = *(const bf16x8*)(ab + (size_t)(m0 + i * 16 + ln) * 64 + koff);
#pragma unroll
    for (int j = 0; j < 4; j++)
      bfr[j] = *(const bf16x8*)(bbp + (size_t)(c0 + j * 16 + ln) * 64 + koff);
#pragma unroll
    for (int i = 0; i < 4; i++)
#pragma unroll
      for (int j = 0; j < 4; j++)
        acc[i][j] = __builtin_amdgcn_mfma_f32_16x16x32_bf16(a[i], bfr[j], acc[i][j], 0, 0, 0);
  }
#pragma unroll
  for (int i = 0; i < 4; i++)
#pragma unroll
    for (int j = 0; j < 4; j++)
#pragma unroll
      for (int r = 0; r < 4; r++)
        Lb[(size_t)(m0 + i * 16 + quad * 4 + r) * N + c0 + j * 16 + ln] = acc[i][j][r];
}

// ---------------- per-row max and 1/sum(exp) ----------------
__global__ __launch_bounds__(256) void rowstat_kernel(
    const float* __restrict__ Lb, float* __restrict__ rmx, float* __restrict__ rinv) {
  const int m = blockIdx.x;
  const float4* row = (const float4*)(Lb + (size_t)m * N);
  float4 v[4];
  float mx = -3.0e38f;
#pragma unroll
  for (int i = 0; i < 4; i++) {
    v[i] = row[threadIdx.x + i * 256];
    mx = fmaxf(mx, fmaxf(fmaxf(v[i].x, v[i].y), fmaxf(v[i].z, v[i].w)));
  }
  for (int off = 32; off; off >>= 1) mx = fmaxf(mx, __shfl_down(mx, off, 64));
  __shared__ float sm[4], ssum[4];
  const int wid = threadIdx.x >> 6, lane = threadIdx.x & 63;
  if (lane == 0) sm[wid] = mx;
  __syncthreads();
  mx = fmaxf(fmaxf(sm[0], sm[1]), fmaxf(sm[2], sm[3]));
  float s = 0.f;
#pragma unroll
  for (int i = 0; i < 4; i++)
    s += __expf(v[i].x - mx) + __expf(v[i].y - mx) + __expf(v[i].z - mx) +
         __expf(v[i].w - mx);
  for (int off = 32; off; off >>= 1) s += __shfl_down(s, off, 64);
  if (lane == 0) ssum[wid] = s;
  __syncthreads();
  if (threadIdx.x == 0) {
    rmx[m] = mx;
    rinv[m] = 1.0f / (ssum[0] + ssum[1] + ssum[2] + ssum[3]);
  }
}

// ---------------- O GEMM: part[ks][d][m] += exp(L[m][c]-mx)*rinv * V[d][c] ----------------
// M=d (4 tiles), N=m (wave-per-16), K=c split 8 ways. Register-direct frags.
__global__ __launch_bounds__(256) void ogemm_kernel(
    const float* __restrict__ Lb, const unsigned short* __restrict__ vbo,
    const float* __restrict__ rmx, const float* __restrict__ rinv,
    float* __restrict__ part) {
  const int w = threadIdx.x >> 6, lane = threadIdx.x & 63;
  const int ln = lane & 15, quad = lane >> 4;
  const int m = blockIdx.x * 64 + w * 16 + ln;
  const int cbase = blockIdx.y * 512;
  const float mxv = rmx[m];
  const float* lrow = Lb + (size_t)m * N;
  f32x4 acc[4];
#pragma unroll
  for (int i = 0; i < 4; i++) acc[i] = (f32x4)(0.f);
  for (int kc = 0; kc < 16; kc++) {
    const int c0 = cbase + kc * 32 + quad * 8;
    bf16x8 a[4];
#pragma unroll
    for (int i = 0; i < 4; i++)
      a[i] = *(const bf16x8*)(vbo + (size_t)(i * 16 + ln) * N + c0);
    float4 l0 = *(const float4*)(lrow + c0);
    float4 l1 = *(const float4*)(lrow + c0 + 4);
    bf16x8 p;
    p[0] = (short)bfc(__expf(l0.x - mxv));
    p[1] = (short)bfc(__expf(l0.y - mxv));
    p[2] = (short)bfc(__expf(l0.z - mxv));
    p[3] = (short)bfc(__expf(l0.w - mxv));
    p[4] = (short)bfc(__expf(l1.x - mxv));
    p[5] = (short)bfc(__expf(l1.y - mxv));
    p[6] = (short)bfc(__expf(l1.z - mxv));
    p[7] = (short)bfc(__expf(l1.w - mxv));
#pragma unroll
    for (int i = 0; i < 4; i++)
      acc[i] = __builtin_amdgcn_mfma_f32_16x16x32_bf16(a[i], p, acc[i], 0, 0, 0);
  }
  const float rv = rinv[m];
#pragma unroll
  for (int i = 0; i < 4; i++)
#pragma unroll
    for (int r = 0; r < 4; r++) {
      int d = i * 16 + quad * 4 + r;
      part[((size_t)blockIdx.y * 64 + d) * N + m] = acc[i][r] * rv;
    }
}

// ---------------- reduce 8 split partials -> d_out slab ----------------
__global__ __launch_bounds__(256) void reduce_kernel(
    const float* __restrict__ part, float* __restrict__ outp) {
  int i = blockIdx.x * 256 + threadIdx.x;
  const float4* p4 = (const float4*)part;
  float4 s = p4[i];
  for (int kS = 1; kS < 8; kS++) {
    float4 u = p4[i + kS * 65536];
    s.x += u.x; s.y += u.y; s.z += u.z; s.w += u.w;
  }
  ((float4*)outp)[i] = s;
}

extern "C" void kernel_launch(void* const* d_in, const int* in_sizes, int n_in,
                              void* d_out, int out_size, void* d_ws, size_t ws_size,
                              hipStream_t stream) {
  const float* x      = (const float*)d_in[0];
  const float* dc_w1  = (const float*)d_in[1];
  const float* dc_b1  = (const float*)d_in[2];
  const float* dc_g1  = (const float*)d_in[3];
  const float* dc_be1 = (const float*)d_in[4];
  const float* dc_w2  = (const float*)d_in[5];
  const float* dc_b2  = (const float*)d_in[6];
  const float* dc_g2  = (const float*)d_in[7];
  const float* dc_be2 = (const float*)d_in[8];
  const float* aspp_w[4] = {(const float*)d_in[9],  (const float*)d_in[12],
                            (const float*)d_in[15], (const float*)d_in[18]};
  const float* aspp_g[4] = {(const float*)d_in[10], (const float*)d_in[13],
                            (const float*)d_in[16], (const float*)d_in[19]};
  const float* aspp_b[4] = {(const float*)d_in[11], (const float*)d_in[14],
                            (const float*)d_in[17], (const float*)d_in[20]};
  const float* wq = (const float*)d_in[21];
  const float* bq = (const float*)d_in[22];
  const float* wk = (const float*)d_in[23];
  const float* bk = (const float*)d_in[24];
  const float* wv = (const float*)d_in[25];
  const float* bv = (const float*)d_in[26];
  const float* rel_h = (const float*)d_in[27];
  const float* rel_w = (const float*)d_in[28];
  float* out = (float*)d_out;

  float* ws = (float*)d_ws;
  size_t off = 0;
  auto alloc = [&](size_t nf) { float* p = ws + off; off += nf; return p; };
  float* P1   = alloc((size_t)4 * 128 * 66 * 66);
  float* P2   = alloc((size_t)4 * 256 * 66 * 66);
  float* P3   = alloc((size_t)4 * 256 * 82 * 82);
  float* t1   = alloc((size_t)4 * 256 * N);
  float* br   = alloc((size_t)4 * 4 * 64 * N);
  float* Lbuf = alloc((size_t)N * N);
  float* part = alloc((size_t)8 * 64 * N);
  float* rmx  = alloc(N);
  float* rinv = alloc(N);
  float* st1  = alloc(512);
  float* st2  = alloc(512);
  float* sta  = alloc(512);
  unsigned short* qT   = (unsigned short*)alloc((size_t)16 * N * 64 / 2);
  unsigned short* kT   = (unsigned short*)alloc((size_t)16 * N * 64 / 2);
  unsigned short* vb   = (unsigned short*)alloc((size_t)16 * N * 64 / 2);
  unsigned short* posT = (unsigned short*)alloc((size_t)N * 64 / 2);

  hipMemsetAsync(P1, 0, (size_t)4 * 128 * 66 * 66 * 4, stream);
  hipMemsetAsync(P2, 0, (size_t)4 * 256 * 66 * 66 * 4, stream);
  hipMemsetAsync(P3, 0, (size_t)4 * 256 * 82 * 82 * 4, stream);

  pool_kernel<<<8192, 256, 0, stream>>>(x, P1);

  conv3x3_kernel<4><<<dim3(4, 64, 4), 256, 0, stream>>>(P1, dc_w1, dc_b1, t1, 128, 1, 1, 256);
  bn_stats_kernel<<<256, 256, 0, stream>>>(t1, dc_g1, dc_be1, st1, 256);
  bn_norm_pad_kernel<<<16384, 256, 0, stream>>>(t1, st1, P2, 255, 1);
  conv3x3_kernel<4><<<dim3(4, 64, 4), 256, 0, stream>>>(P2, dc_w2, dc_b2, t1, 256, 1, 1, 256);
  bn_stats_kernel<<<256, 256, 0, stream>>>(t1, dc_g2, dc_be2, st2, 256);
  bn_norm_pad_kernel<<<16384, 256, 0, stream>>>(t1, st2, P3, 255, 9);

  aspp1_kernel<<<dim3(16, 4, 4), 256, 0, stream>>>(P3, aspp_w[0], br);
  const int dils[3] = {3, 6, 9};
  for (int kbr = 1; kbr < 4; kbr++)
    conv3x3_kernel<2><<<dim3(4, 32, 4), 256, 0, stream>>>(
        P3, aspp_w[kbr], nullptr, br + (size_t)kbr * 1048576, 256, dils[kbr - 1], 9, 64);
  for (int kbr = 0; kbr < 4; kbr++) {
    bn_stats_kernel<<<64, 256, 0, stream>>>(br + (size_t)kbr * 1048576,
                                            aspp_g[kbr], aspp_b[kbr],
                                            sta + kbr * 128, 64);
    bn_norm_kernel<<<4096, 256, 0, stream>>>(br + (size_t)kbr * 1048576,
                                             sta + kbr * 128, 63);
  }

  qkv_kernel<<<dim3(16, 12, 16), 256, 0, stream>>>(br, wq, bq, wk, bk, wv, bv,
                                                   qT, kT, vb);
  posT_kernel<<<256, 256, 0, stream>>>(rel_h, rel_w, posT);

  for (int bb = 0; bb < 16; bb++) {
    const int kbr = bb >> 2, b = bb & 3;
    const size_t slab = (size_t)bb * N * 64;
    lgemm_kernel<<<dim3(32, 32), 256, 0, stream>>>(qT + slab, kT + slab, posT, Lbuf);
    rowstat_kernel<<<4096, 256, 0, stream>>>(Lbuf, rmx, rinv);
    ogemm_kernel<<<dim3(64, 8), 256, 0, stream>>>(Lbuf, vb + slab, rmx, rinv, part);
    reduce_kernel<<<256, 256, 0, stream>>>(
        part, out + ((size_t)b * 256 + (size_t)kbr * 64) * N);
  }
}

// Round 3
// 1556.746 us; speedup vs baseline: 3.2049x; 1.4154x over previous
//
#include <hip/hip_runtime.h>
#include <math.h>

constexpr int Bn = 4;
constexpr int S  = 64;
constexpr int N  = 4096;  // S*S

#define DEV static __device__ __forceinline__

typedef __attribute__((ext_vector_type(8))) short bf16x8;
typedef __attribute__((ext_vector_type(4))) float f32x4;

DEV unsigned short bfc(float x) {  // f32 -> bf16 RNE
  unsigned u = __float_as_uint(x);
  unsigned r = (u + 0x7FFFu + ((u >> 16) & 1u)) >> 16;
  return (unsigned short)r;
}

DEV void fma4(float4& a, float s, const float4 u) {
  a.x = fmaf(s, u.x, a.x); a.y = fmaf(s, u.y, a.y);
  a.z = fmaf(s, u.z, a.z); a.w = fmaf(s, u.w, a.w);
}

// ---------------- weight transpose: src[Cout][Cin][T] f32 -> dst[T][Cout][Cin] bf16 ----
__global__ __launch_bounds__(256) void wtr_kernel(const float* __restrict__ src,
                                                  unsigned short* __restrict__ dst,
                                                  int Cout, int Cin, int T) {
  int i = blockIdx.x * 256 + threadIdx.x;  // i = (t*Cout + co)*Cin + ci
  int ci = i % Cin;
  int r  = i / Cin;
  int t  = r / Cout;
  int co = r - t * Cout;
  dst[i] = bfc(src[((size_t)co * Cin + ci) * T + t]);
}

// ---------------- maxpool 2x2 -> NHWC bf16 padded (halo=1) ----------------
// Pp1[b][66][66][128]
__global__ __launch_bounds__(256) void pool_kernel(const float* __restrict__ x,
                                                   unsigned short* __restrict__ Pp1) {
  int i = blockIdx.x * 256 + threadIdx.x;  // 4*128*64*16 = 524288
  int xg = i & 15, y = (i >> 4) & 63, c = (i >> 10) & 127, b = i >> 17;
  const float* s = x + (((size_t)(b * 128 + c) * 128) + 2 * y) * 128 + 8 * xg;
  float4 u0 = *(const float4*)(s), u1 = *(const float4*)(s + 4);
  float4 u2 = *(const float4*)(s + 128), u3 = *(const float4*)(s + 132);
  float m0 = fmaxf(fmaxf(u0.x, u0.y), fmaxf(u2.x, u2.y));
  float m1 = fmaxf(fmaxf(u0.z, u0.w), fmaxf(u2.z, u2.w));
  float m2 = fmaxf(fmaxf(u1.x, u1.y), fmaxf(u3.x, u3.y));
  float m3 = fmaxf(fmaxf(u1.z, u1.w), fmaxf(u3.z, u3.w));
  unsigned short* d = Pp1 + (((size_t)b * 66 + y + 1) * 66 + xg * 4 + 1) * 128 + c;
  d[0] = bfc(m0); d[128] = bfc(m1); d[256] = bfc(m2); d[384] = bfc(m3);
}

// ---------------- dc conv: implicit GEMM, 9 taps, Cout=256 ----------------
// in: NHWC bf16 padded (halo=1==dil), wt: [9][256][CIN] bf16, out: [b][256][N] f32.
// Block: 64co x 128n (4 waves of 64co x 32n; a[4], b[2]).
template <int CIN>
__global__ __launch_bounds__(256) void dcconv_kernel(
    const unsigned short* __restrict__ in, const unsigned short* __restrict__ wt,
    float* __restrict__ out) {
  const int Wp = 66;
  const int w = threadIdx.x >> 6, lane = threadIdx.x & 63;
  const int ln = lane & 15, quad = lane >> 4;
  const int b = blockIdx.z, co0 = blockIdx.y * 64;
  const int n0 = blockIdx.x * 128 + w * 32;
  const unsigned short* inb = in + (size_t)b * Wp * Wp * CIN;
  size_t pix[2];
#pragma unroll
  for (int j = 0; j < 2; j++) {
    int n = n0 + j * 16 + ln;
    int y = n >> 6, x = n & 63;
    pix[j] = ((size_t)y * Wp + x) * CIN;  // hd = halo - dil = 0
  }
  f32x4 acc[4][2];
#pragma unroll
  for (int i = 0; i < 4; i++)
#pragma unroll
    for (int j = 0; j < 2; j++) acc[i][j] = (f32x4)(0.f);
#pragma unroll
  for (int ky = 0; ky < 3; ky++)
#pragma unroll
    for (int kx = 0; kx < 3; kx++) {
      const size_t toff = ((size_t)ky * Wp + kx) * CIN;
      const unsigned short* wtap = wt + (size_t)(ky * 3 + kx) * 256 * CIN;
      for (int kc = 0; kc < CIN / 32; kc++) {
        const int ko = kc * 32 + quad * 8;
        bf16x8 a[4], bb[2];
#pragma unroll
        for (int i = 0; i < 4; i++)
          a[i] = *(const bf16x8*)(wtap + (size_t)(co0 + i * 16 + ln) * CIN + ko);
#pragma unroll
        for (int j = 0; j < 2; j++)
          bb[j] = *(const bf16x8*)(inb + pix[j] + toff + ko);
#pragma unroll
        for (int i = 0; i < 4; i++)
#pragma unroll
          for (int j = 0; j < 2; j++)
            acc[i][j] = __builtin_amdgcn_mfma_f32_16x16x32_bf16(a[i], bb[j], acc[i][j], 0, 0, 0);
      }
    }
#pragma unroll
  for (int i = 0; i < 4; i++)
#pragma unroll
    for (int j = 0; j < 2; j++)
#pragma unroll
      for (int r = 0; r < 4; r++)
        out[((size_t)(b * 256 + co0 + i * 16 + quad * 4 + r)) * N + n0 + j * 16 + ln] =
            acc[i][j][r];
}

// ---------------- all 4 ASPP branches, implicit GEMM on Pp3 (halo=9) ----------------
// wtall: [4][9][64][256] bf16 (branch 0 = 1x1, stored at tap slot 4).
// out br: [branch*4+b][64][N] f32. Block 64co x 64n as 2x2 waves of 32x32.
__global__ __launch_bounds__(256) void branch_kernel(
    const unsigned short* __restrict__ in, const unsigned short* __restrict__ wtall,
    float* __restrict__ br) {
  const int Wp = 82, halo = 9, CIN = 256;
  const int w = threadIdx.x >> 6, lane = threadIdx.x & 63;
  const int ln = lane & 15, quad = lane >> 4;
  const int bb = blockIdx.y;
  const int kbr = bb >> 2, b = bb & 3;
  const int dil = (kbr == 0) ? 1 : 3 * kbr;
  const int klo = (kbr == 0) ? 1 : 0, khi = (kbr == 0) ? 2 : 3;
  const int hd = halo - dil;
  const int cw = (w & 1) * 32, nw = (w >> 1) * 32;
  const int n0 = blockIdx.x * 64 + nw;
  const unsigned short* inb = in + (size_t)b * Wp * Wp * CIN;
  size_t pix[2];
#pragma unroll
  for (int j = 0; j < 2; j++) {
    int n = n0 + j * 16 + ln;
    int y = n >> 6, x = n & 63;
    pix[j] = ((size_t)(y + hd) * Wp + x + hd) * CIN;
  }
  f32x4 acc[2][2];
#pragma unroll
  for (int i = 0; i < 2; i++)
#pragma unroll
    for (int j = 0; j < 2; j++) acc[i][j] = (f32x4)(0.f);
  for (int ky = klo; ky < khi; ky++)
    for (int kx = klo; kx < khi; kx++) {
      const size_t toff = ((size_t)ky * Wp + kx) * dil * CIN;
      const unsigned short* wtap =
          wtall + ((size_t)kbr * 9 + ky * 3 + kx) * 64 * CIN;
      for (int kc = 0; kc < CIN / 32; kc++) {
        const int ko = kc * 32 + quad * 8;
        bf16x8 a[2], bv[2];
#pragma unroll
        for (int i = 0; i < 2; i++)
          a[i] = *(const bf16x8*)(wtap + (size_t)(cw + i * 16 + ln) * CIN + ko);
#pragma unroll
        for (int j = 0; j < 2; j++)
          bv[j] = *(const bf16x8*)(inb + pix[j] + toff + ko);
#pragma unroll
        for (int i = 0; i < 2; i++)
#pragma unroll
          for (int j = 0; j < 2; j++)
            acc[i][j] = __builtin_amdgcn_mfma_f32_16x16x32_bf16(a[i], bv[j], acc[i][j], 0, 0, 0);
      }
    }
#pragma unroll
  for (int i = 0; i < 2; i++)
#pragma unroll
    for (int j = 0; j < 2; j++)
#pragma unroll
      for (int r = 0; r < 4; r++)
        br[((size_t)bb * 64 + cw + i * 16 + quad * 4 + r) * N + n0 + j * 16 + ln] =
            acc[i][j][r];
}

// ---------------- BN training-mode stats -> per-channel scale/shift ----------------
__global__ __launch_bounds__(256) void bn_stats_kernel(
    const float* __restrict__ t, const float* __restrict__ gamma,
    const float* __restrict__ beta, float* __restrict__ ss, int C) {
  const int c = blockIdx.x;
  float s = 0.f, s2 = 0.f;
  for (int b = 0; b < Bn; b++) {
    const float* p = t + ((size_t)(b * C + c)) * N;
    for (int i = threadIdx.x; i < N; i += 256) {
      float v = p[i];
      s += v; s2 = fmaf(v, v, s2);
    }
  }
  for (int off = 32; off; off >>= 1) {
    s += __shfl_down(s, off, 64);
    s2 += __shfl_down(s2, off, 64);
  }
  __shared__ float rs[4], rs2[4];
  const int wid = threadIdx.x >> 6, lane = threadIdx.x & 63;
  if (lane == 0) { rs[wid] = s; rs2[wid] = s2; }
  __syncthreads();
  if (threadIdx.x == 0) {
    float S1 = rs[0] + rs[1] + rs[2] + rs[3];
    float S2 = rs2[0] + rs2[1] + rs2[2] + rs2[3];
    const float cnt = (float)(Bn * N);
    float mean = S1 / cnt;
    float var = S2 / cnt - mean * mean;
    float sc = gamma[c] * rsqrtf(var + 1e-5f);
    ss[2 * c] = sc;
    ss[2 * c + 1] = beta[c] - mean * sc;
  }
}

// ---------------- BN+ReLU -> NHWC bf16 padded buffer (C=256) ----------------
__global__ __launch_bounds__(256) void bn_norm_pad_kernel(
    const float* __restrict__ t, const float* __restrict__ ss,
    unsigned short* __restrict__ outp, int Wp, int halo) {
  int i = blockIdx.x * 256 + threadIdx.x;  // (b*64+cg)*4096+n, 1048576 total
  int n = i & 4095, cg = (i >> 12) & 63, b = i >> 18;
  int c0 = cg * 4;
  ushort4 pk;
  float v0 = fmaxf(fmaf(t[((size_t)(b * 256 + c0 + 0)) * N + n], ss[2 * (c0 + 0)], ss[2 * (c0 + 0) + 1]), 0.f);
  float v1 = fmaxf(fmaf(t[((size_t)(b * 256 + c0 + 1)) * N + n], ss[2 * (c0 + 1)], ss[2 * (c0 + 1) + 1]), 0.f);
  float v2 = fmaxf(fmaf(t[((size_t)(b * 256 + c0 + 2)) * N + n], ss[2 * (c0 + 2)], ss[2 * (c0 + 2) + 1]), 0.f);
  float v3 = fmaxf(fmaf(t[((size_t)(b * 256 + c0 + 3)) * N + n], ss[2 * (c0 + 3)], ss[2 * (c0 + 3) + 1]), 0.f);
  pk.x = bfc(v0); pk.y = bfc(v1); pk.z = bfc(v2); pk.w = bfc(v3);
  int y = n >> 6, x = n & 63;
  *(ushort4*)(outp + (((size_t)b * Wp + y + halo) * Wp + x + halo) * 256 + c0) = pk;
}

// normalize+ReLU in place (ASPP branch outputs, fp32)
__global__ __launch_bounds__(256) void bn_norm_kernel(
    float* __restrict__ t, const float* __restrict__ ss, int Cmask) {
  int i = blockIdx.x * 256 + threadIdx.x;
  int c = (i >> 12) & Cmask;
  t[i] = fmaxf(fmaf(t[i], ss[2 * c], ss[2 * c + 1]), 0.f);
}

// ---------------- q/k/v 1x1 convs -> bf16 MFMA-layout buffers ----------------
__global__ __launch_bounds__(256) void qkv_kernel(
    const float* __restrict__ br,
    const float* __restrict__ wq, const float* __restrict__ bq,
    const float* __restrict__ wk, const float* __restrict__ bk,
    const float* __restrict__ wv, const float* __restrict__ bvb,
    unsigned short* __restrict__ qTo, unsigned short* __restrict__ kTo,
    unsigned short* __restrict__ vbo) {
  const int bb = blockIdx.z;
  const int p = blockIdx.y >> 2, dg = blockIdx.y & 3;
  const float* w  = p == 0 ? wq : (p == 1 ? wk : wv);
  const float* bi = p == 0 ? bq : (p == 1 ? bk : bvb);
  __shared__ float wl[64 * 16];
  const int d0b = dg * 16;
  for (int i = threadIdx.x; i < 64 * 16; i += 256)
    wl[i] = w[(size_t)(d0b + (i & 15)) * 64 + (i >> 4)];
  __syncthreads();
  const int tn = threadIdx.x & 63, td = threadIdx.x >> 6;
  const int n0 = blockIdx.x * 256 + tn * 4;
  const int d0 = d0b + td * 4;
  const float* inb = br + (size_t)bb * 64 * N;
  float4 acc[4];
#pragma unroll
  for (int j = 0; j < 4; j++) {
    float bvv = bi[d0 + j];
    acc[j] = make_float4(bvv, bvv, bvv, bvv);
  }
  for (int ci = 0; ci < 64; ci++) {
    float4 u = *(const float4*)(inb + (size_t)ci * N + n0);
    float4 wv4 = *(const float4*)(wl + ci * 16 + td * 4);
    fma4(acc[0], wv4.x, u); fma4(acc[1], wv4.y, u);
    fma4(acc[2], wv4.z, u); fma4(acc[3], wv4.w, u);
  }
  const size_t slab = (size_t)bb * N * 64;
  if (p < 2) {
    unsigned short* o = (p == 0 ? qTo : kTo) + slab;
#pragma unroll
    for (int nn = 0; nn < 4; nn++) {
      ushort4 pk;
      pk.x = bfc(((const float*)&acc[0])[nn]);
      pk.y = bfc(((const float*)&acc[1])[nn]);
      pk.z = bfc(((const float*)&acc[2])[nn]);
      pk.w = bfc(((const float*)&acc[3])[nn]);
      *(ushort4*)(o + (size_t)(n0 + nn) * 64 + d0) = pk;
    }
  } else {
    unsigned short* o = vbo + slab;
#pragma unroll
    for (int j = 0; j < 4; j++) {
      ushort4 pk;
      pk.x = bfc(acc[j].x); pk.y = bfc(acc[j].y);
      pk.z = bfc(acc[j].z); pk.w = bfc(acc[j].w);
      *(ushort4*)(o + (size_t)(d0 + j) * N + n0) = pk;
    }
  }
}

// ---------------- posT[n][d] = rel_w[d][h] + rel_h[d][w], bf16 ----------------
__global__ __launch_bounds__(256) void posT_kernel(
    const float* __restrict__ rel_h, const float* __restrict__ rel_w,
    unsigned short* __restrict__ posT) {
  int i = blockIdx.x * 256 + threadIdx.x;  // 65536
  int n = i >> 4, dq = (i & 15) * 4;
  int h = n >> 6, wc = n & 63;
  ushort4 pk;
  pk.x = bfc(rel_w[(dq + 0) * 64 + h] + rel_h[(dq + 0) * 64 + wc]);
  pk.y = bfc(rel_w[(dq + 1) * 64 + h] + rel_h[(dq + 1) * 64 + wc]);
  pk.z = bfc(rel_w[(dq + 2) * 64 + h] + rel_h[(dq + 2) * 64 + wc]);
  pk.w = bfc(rel_w[(dq + 3) * 64 + h] + rel_h[(dq + 3) * 64 + wc]);
  *(ushort4*)(posT + (size_t)n * 64 + dq) = pk;
}

// ---------------- logits: L[m][c] = sum_k [q;pos][m][k]*[k;q][c][k] ----------------
__global__ __launch_bounds__(256) void lgemm_kernel(
    const unsigned short* __restrict__ qT, const unsigned short* __restrict__ kT,
    const unsigned short* __restrict__ posT, float* __restrict__ Lb) {
  const int w = threadIdx.x >> 6, lane = threadIdx.x & 63;
  const int ln = lane & 15, quad = lane >> 4;
  const int m0 = blockIdx.x * 128 + (w & 1) * 64;
  const int c0 = blockIdx.y * 128 + (w >> 1) * 64;
  f32x4 acc[4][4];
#pragma unroll
  for (int i = 0; i < 4; i++)
#pragma unroll
    for (int j = 0; j < 4; j++) acc[i][j] = (f32x4)(0.f);
#pragma unroll
  for (int s = 0; s < 4; s++) {
    const int koff = (s & 1) * 32 + quad * 8;
    const unsigned short* ab = (s < 2) ? qT : posT;
    const unsigned short* bbp = (s < 2) ? kT : qT;
    bf16x8 a[4], bfr[4];
#pragma unroll
    for (int i = 0; i < 4; i++)
      a[i] = *(const bf16x8*)(ab + (size_t)(m0 + i * 16 + ln) * 64 + koff);
#pragma unroll
    for (int j = 0; j < 4; j++)
      bfr[j] = *(const bf16x8*)(bbp + (size_t)(c0 + j * 16 + ln) * 64 + koff);
#pragma unroll
    for (int i = 0; i < 4; i++)
#pragma unroll
      for (int j = 0; j < 4; j++)
        acc[i][j] = __builtin_amdgcn_mfma_f32_16x16x32_bf16(a[i], bfr[j], acc[i][j], 0, 0, 0);
  }
#pragma unroll
  for (int i = 0; i < 4; i++)
#pragma unroll
    for (int j = 0; j < 4; j++)
#pragma unroll
      for (int r = 0; r < 4; r++)
        Lb[(size_t)(m0 + i * 16 + quad * 4 + r) * N + c0 + j * 16 + ln] = acc[i][j][r];
}

// ---------------- per-row max and 1/sum(exp) ----------------
__global__ __launch_bounds__(256) void rowstat_kernel(
    const float* __restrict__ Lb, float* __restrict__ rmx, float* __restrict__ rinv) {
  const int m = blockIdx.x;
  const float4* row = (const float4*)(Lb + (size_t)m * N);
  float4 v[4];
  float mx = -3.0e38f;
#pragma unroll
  for (int i = 0; i < 4; i++) {
    v[i] = row[threadIdx.x + i * 256];
    mx = fmaxf(mx, fmaxf(fmaxf(v[i].x, v[i].y), fmaxf(v[i].z, v[i].w)));
  }
  for (int off = 32; off; off >>= 1) mx = fmaxf(mx, __shfl_down(mx, off, 64));
  __shared__ float sm[4], ssum[4];
  const int wid = threadIdx.x >> 6, lane = threadIdx.x & 63;
  if (lane == 0) sm[wid] = mx;
  __syncthreads();
  mx = fmaxf(fmaxf(sm[0], sm[1]), fmaxf(sm[2], sm[3]));
  float s = 0.f;
#pragma unroll
  for (int i = 0; i < 4; i++)
    s += __expf(v[i].x - mx) + __expf(v[i].y - mx) + __expf(v[i].z - mx) +
         __expf(v[i].w - mx);
  for (int off = 32; off; off >>= 1) s += __shfl_down(s, off, 64);
  if (lane == 0) ssum[wid] = s;
  __syncthreads();
  if (threadIdx.x == 0) {
    rmx[m] = mx;
    rinv[m] = 1.0f / (ssum[0] + ssum[1] + ssum[2] + ssum[3]);
  }
}

// ---------------- O GEMM ----------------
__global__ __launch_bounds__(256) void ogemm_kernel(
    const float* __restrict__ Lb, const unsigned short* __restrict__ vbo,
    const float* __restrict__ rmx, const float* __restrict__ rinv,
    float* __restrict__ part) {
  const int w = threadIdx.x >> 6, lane = threadIdx.x & 63;
  const int ln = lane & 15, quad = lane >> 4;
  const int m = blockIdx.x * 64 + w * 16 + ln;
  const int cbase = blockIdx.y * 512;
  const float mxv = rmx[m];
  const float* lrow = Lb + (size_t)m * N;
  f32x4 acc[4];
#pragma unroll
  for (int i = 0; i < 4; i++) acc[i] = (f32x4)(0.f);
  for (int kc = 0; kc < 16; kc++) {
    const int c0 = cbase + kc * 32 + quad * 8;
    bf16x8 a[4];
#pragma unroll
    for (int i = 0; i < 4; i++)
      a[i] = *(const bf16x8*)(vbo + (size_t)(i * 16 + ln) * N + c0);
    float4 l0 = *(const float4*)(lrow + c0);
    float4 l1 = *(const float4*)(lrow + c0 + 4);
    bf16x8 p;
    p[0] = (short)bfc(__expf(l0.x - mxv));
    p[1] = (short)bfc(__expf(l0.y - mxv));
    p[2] = (short)bfc(__expf(l0.z - mxv));
    p[3] = (short)bfc(__expf(l0.w - mxv));
    p[4] = (short)bfc(__expf(l1.x - mxv));
    p[5] = (short)bfc(__expf(l1.y - mxv));
    p[6] = (short)bfc(__expf(l1.z - mxv));
    p[7] = (short)bfc(__expf(l1.w - mxv));
#pragma unroll
    for (int i = 0; i < 4; i++)
      acc[i] = __builtin_amdgcn_mfma_f32_16x16x32_bf16(a[i], p, acc[i], 0, 0, 0);
  }
  const float rv = rinv[m];
#pragma unroll
  for (int i = 0; i < 4; i++)
#pragma unroll
    for (int r = 0; r < 4; r++) {
      int d = i * 16 + quad * 4 + r;
      part[((size_t)blockIdx.y * 64 + d) * N + m] = acc[i][r] * rv;
    }
}

// ---------------- reduce 8 split partials -> d_out slab ----------------
__global__ __launch_bounds__(256) void reduce_kernel(
    const float* __restrict__ part, float* __restrict__ outp) {
  int i = blockIdx.x * 256 + threadIdx.x;
  const float4* p4 = (const float4*)part;
  float4 s = p4[i];
  for (int kS = 1; kS < 8; kS++) {
    float4 u = p4[i + kS * 65536];
    s.x += u.x; s.y += u.y; s.z += u.z; s.w += u.w;
  }
  ((float4*)outp)[i] = s;
}

extern "C" void kernel_launch(void* const* d_in, const int* in_sizes, int n_in,
                              void* d_out, int out_size, void* d_ws, size_t ws_size,
                              hipStream_t stream) {
  const float* x      = (const float*)d_in[0];
  const float* dc_w1  = (const float*)d_in[1];
  const float* dc_g1  = (const float*)d_in[3];
  const float* dc_be1 = (const float*)d_in[4];
  const float* dc_w2  = (const float*)d_in[5];
  const float* dc_g2  = (const float*)d_in[7];
  const float* dc_be2 = (const float*)d_in[8];
  const float* aspp_w[4] = {(const float*)d_in[9],  (const float*)d_in[12],
                            (const float*)d_in[15], (const float*)d_in[18]};
  const float* aspp_g[4] = {(const float*)d_in[10], (const float*)d_in[13],
                            (const float*)d_in[16], (const float*)d_in[19]};
  const float* aspp_b[4] = {(const float*)d_in[11], (const float*)d_in[14],
                            (const float*)d_in[17], (const float*)d_in[20]};
  const float* wq = (const float*)d_in[21];
  const float* bq = (const float*)d_in[22];
  const float* wk = (const float*)d_in[23];
  const float* bk = (const float*)d_in[24];
  const float* wv = (const float*)d_in[25];
  const float* bv = (const float*)d_in[26];
  const float* rel_h = (const float*)d_in[27];
  const float* rel_w = (const float*)d_in[28];
  float* out = (float*)d_out;

  float* ws = (float*)d_ws;
  size_t off = 0;
  auto alloc = [&](size_t nf) { float* p = ws + off; off += nf; return p; };
  unsigned short* Pp1 = (unsigned short*)alloc((size_t)4 * 66 * 66 * 128 / 2 + 64);
  unsigned short* Pp2 = (unsigned short*)alloc((size_t)4 * 66 * 66 * 256 / 2 + 64);
  unsigned short* Pp3 = (unsigned short*)alloc((size_t)4 * 82 * 82 * 256 / 2 + 64);
  float* t1   = alloc((size_t)4 * 256 * N);
  float* br   = alloc((size_t)4 * 4 * 64 * N);
  float* Lbuf = alloc((size_t)N * N);
  float* part = alloc((size_t)8 * 64 * N);
  float* rmx  = alloc(N);
  float* rinv = alloc(N);
  float* st1  = alloc(512);
  float* st2  = alloc(512);
  float* sta  = alloc(512);
  unsigned short* qT    = (unsigned short*)alloc((size_t)16 * N * 64 / 2);
  unsigned short* kT    = (unsigned short*)alloc((size_t)16 * N * 64 / 2);
  unsigned short* vb    = (unsigned short*)alloc((size_t)16 * N * 64 / 2);
  unsigned short* posT  = (unsigned short*)alloc((size_t)N * 64 / 2);
  unsigned short* wt1   = (unsigned short*)alloc((size_t)9 * 256 * 128 / 2);
  unsigned short* wt2   = (unsigned short*)alloc((size_t)9 * 256 * 256 / 2);
  unsigned short* wtbr  = (unsigned short*)alloc((size_t)4 * 9 * 64 * 256 / 2);

  hipMemsetAsync(Pp1, 0, (size_t)4 * 66 * 66 * 128 * 2, stream);
  hipMemsetAsync(Pp2, 0, (size_t)4 * 66 * 66 * 256 * 2, stream);
  hipMemsetAsync(Pp3, 0, (size_t)4 * 82 * 82 * 256 * 2, stream);
  hipMemsetAsync(wtbr, 0, (size_t)4 * 9 * 64 * 256 * 2, stream);

  // weight prep
  wtr_kernel<<<(9 * 256 * 128) / 256, 256, 0, stream>>>(dc_w1, wt1, 256, 128, 9);
  wtr_kernel<<<(9 * 256 * 256) / 256, 256, 0, stream>>>(dc_w2, wt2, 256, 256, 9);
  // branch 0 (1x1) goes into tap slot 4 (center); branches 1-3 full 9 taps
  wtr_kernel<<<(64 * 256) / 256, 256, 0, stream>>>(
      aspp_w[0], wtbr + (size_t)4 * 64 * 256, 64, 256, 1);
  for (int kbr = 1; kbr < 4; kbr++)
    wtr_kernel<<<(9 * 64 * 256) / 256, 256, 0, stream>>>(
        aspp_w[kbr], wtbr + (size_t)kbr * 9 * 64 * 256, 64, 256, 9);

  pool_kernel<<<2048, 256, 0, stream>>>(x, Pp1);

  dcconv_kernel<128><<<dim3(32, 4, 4), 256, 0, stream>>>(Pp1, wt1, t1);
  bn_stats_kernel<<<256, 256, 0, stream>>>(t1, dc_g1, dc_be1, st1, 256);
  bn_norm_pad_kernel<<<4096, 256, 0, stream>>>(t1, st1, Pp2, 66, 1);
  dcconv_kernel<256><<<dim3(32, 4, 4), 256, 0, stream>>>(Pp2, wt2, t1);
  bn_stats_kernel<<<256, 256, 0, stream>>>(t1, dc_g2, dc_be2, st2, 256);
  bn_norm_pad_kernel<<<4096, 256, 0, stream>>>(t1, st2, Pp3, 82, 9);

  branch_kernel<<<dim3(64, 16), 256, 0, stream>>>(Pp3, wtbr, br);
  for (int kbr = 0; kbr < 4; kbr++) {
    bn_stats_kernel<<<64, 256, 0, stream>>>(br + (size_t)kbr * 1048576,
                                            aspp_g[kbr], aspp_b[kbr],
                                            sta + kbr * 128, 64);
    bn_norm_kernel<<<4096, 256, 0, stream>>>(br + (size_t)kbr * 1048576,
                                             sta + kbr * 128, 63);
  }

  qkv_kernel<<<dim3(16, 12, 16), 256, 0, stream>>>(br, wq, bq, wk, bk, wv, bv,
                                                   qT, kT, vb);
  posT_kernel<<<256, 256, 0, stream>>>(rel_h, rel_w, posT);

  for (int bb = 0; bb < 16; bb++) {
    const int kbr = bb >> 2, b = bb & 3;
    const size_t slab = (size_t)bb * N * 64;
    lgemm_kernel<<<dim3(32, 32), 256, 0, stream>>>(qT + slab, kT + slab, posT, Lbuf);
    rowstat_kernel<<<4096, 256, 0, stream>>>(Lbuf, rmx, rinv);
    ogemm_kernel<<<dim3(64, 8), 256, 0, stream>>>(Lbuf, vb + slab, rmx, rinv, part);
    reduce_kernel<<<256, 256, 0, stream>>>(
        part, out + ((size_t)b * 256 + (size_t)kbr * 64) * N);
  }
}

// Round 4
// 1279.306 us; speedup vs baseline: 3.8999x; 1.2169x over previous
//
#include <hip/hip_runtime.h>
#include <math.h>

constexpr int Bn = 4;
constexpr int S  = 64;
constexpr int N  = 4096;  // S*S

#define DEV static __device__ __forceinline__

typedef __attribute__((ext_vector_type(8))) short bf16x8;
typedef __attribute__((ext_vector_type(4))) float f32x4;

DEV unsigned short bfc(float x) {  // f32 -> bf16 RNE
  unsigned u = __float_as_uint(x);
  unsigned r = (u + 0x7FFFu + ((u >> 16) & 1u)) >> 16;
  return (unsigned short)r;
}

DEV void fma4(float4& a, float s, const float4 u) {
  a.x = fmaf(s, u.x, a.x); a.y = fmaf(s, u.y, a.y);
  a.z = fmaf(s, u.z, a.z); a.w = fmaf(s, u.w, a.w);
}

// ---------------- weight transpose: src[Cout][Cin][T] f32 -> dst[T][Cout][Cin] bf16 ----
__global__ __launch_bounds__(256) void wtr_kernel(const float* __restrict__ src,
                                                  unsigned short* __restrict__ dst,
                                                  int Cout, int Cin, int T) {
  int i = blockIdx.x * 256 + threadIdx.x;
  int ci = i % Cin;
  int r  = i / Cin;
  int t  = r / Cout;
  int co = r - t * Cout;
  dst[i] = bfc(src[((size_t)co * Cin + ci) * T + t]);
}

// ---------------- maxpool 2x2 -> NHWC bf16 padded (halo=1) ----------------
__global__ __launch_bounds__(256) void pool_kernel(const float* __restrict__ x,
                                                   unsigned short* __restrict__ Pp1) {
  int i = blockIdx.x * 256 + threadIdx.x;  // 524288
  int xg = i & 15, y = (i >> 4) & 63, c = (i >> 10) & 127, b = i >> 17;
  const float* s = x + (((size_t)(b * 128 + c) * 128) + 2 * y) * 128 + 8 * xg;
  float4 u0 = *(const float4*)(s), u1 = *(const float4*)(s + 4);
  float4 u2 = *(const float4*)(s + 128), u3 = *(const float4*)(s + 132);
  float m0 = fmaxf(fmaxf(u0.x, u0.y), fmaxf(u2.x, u2.y));
  float m1 = fmaxf(fmaxf(u0.z, u0.w), fmaxf(u2.z, u2.w));
  float m2 = fmaxf(fmaxf(u1.x, u1.y), fmaxf(u3.x, u3.y));
  float m3 = fmaxf(fmaxf(u1.z, u1.w), fmaxf(u3.z, u3.w));
  unsigned short* d = Pp1 + (((size_t)b * 66 + y + 1) * 66 + xg * 4 + 1) * 128 + c;
  d[0] = bfc(m0); d[128] = bfc(m1); d[256] = bfc(m2); d[384] = bfc(m3);
}

// ---------------- dc conv: implicit GEMM, 9 taps, Cout=256 ----------------
template <int CIN>
__global__ __launch_bounds__(256) void dcconv_kernel(
    const unsigned short* __restrict__ in, const unsigned short* __restrict__ wt,
    float* __restrict__ out) {
  const int Wp = 66;
  const int w = threadIdx.x >> 6, lane = threadIdx.x & 63;
  const int ln = lane & 15, quad = lane >> 4;
  const int b = blockIdx.z, co0 = blockIdx.y * 64;
  const int n0 = blockIdx.x * 128 + w * 32;
  const unsigned short* inb = in + (size_t)b * Wp * Wp * CIN;
  size_t pix[2];
#pragma unroll
  for (int j = 0; j < 2; j++) {
    int n = n0 + j * 16 + ln;
    int y = n >> 6, x = n & 63;
    pix[j] = ((size_t)y * Wp + x) * CIN;
  }
  f32x4 acc[4][2];
#pragma unroll
  for (int i = 0; i < 4; i++)
#pragma unroll
    for (int j = 0; j < 2; j++) acc[i][j] = (f32x4)(0.f);
#pragma unroll
  for (int ky = 0; ky < 3; ky++)
#pragma unroll
    for (int kx = 0; kx < 3; kx++) {
      const size_t toff = ((size_t)ky * Wp + kx) * CIN;
      const unsigned short* wtap = wt + (size_t)(ky * 3 + kx) * 256 * CIN;
      for (int kc = 0; kc < CIN / 32; kc++) {
        const int ko = kc * 32 + quad * 8;
        bf16x8 a[4], bb[2];
#pragma unroll
        for (int i = 0; i < 4; i++)
          a[i] = *(const bf16x8*)(wtap + (size_t)(co0 + i * 16 + ln) * CIN + ko);
#pragma unroll
        for (int j = 0; j < 2; j++)
          bb[j] = *(const bf16x8*)(inb + pix[j] + toff + ko);
#pragma unroll
        for (int i = 0; i < 4; i++)
#pragma unroll
          for (int j = 0; j < 2; j++)
            acc[i][j] = __builtin_amdgcn_mfma_f32_16x16x32_bf16(a[i], bb[j], acc[i][j], 0, 0, 0);
      }
    }
#pragma unroll
  for (int i = 0; i < 4; i++)
#pragma unroll
    for (int j = 0; j < 2; j++)
#pragma unroll
      for (int r = 0; r < 4; r++)
        out[((size_t)(b * 256 + co0 + i * 16 + quad * 4 + r)) * N + n0 + j * 16 + ln] =
            acc[i][j][r];
}

// ---------------- all 4 ASPP branches, implicit GEMM on Pp3 (halo=9) ----------------
__global__ __launch_bounds__(256) void branch_kernel(
    const unsigned short* __restrict__ in, const unsigned short* __restrict__ wtall,
    float* __restrict__ br) {
  const int Wp = 82, halo = 9, CIN = 256;
  const int w = threadIdx.x >> 6, lane = threadIdx.x & 63;
  const int ln = lane & 15, quad = lane >> 4;
  const int bb = blockIdx.y;
  const int kbr = bb >> 2, b = bb & 3;
  const int dil = (kbr == 0) ? 1 : 3 * kbr;
  const int klo = (kbr == 0) ? 1 : 0, khi = (kbr == 0) ? 2 : 3;
  const int hd = halo - dil;
  const int cw = (w & 1) * 32, nw = (w >> 1) * 32;
  const int n0 = blockIdx.x * 64 + nw;
  const unsigned short* inb = in + (size_t)b * Wp * Wp * CIN;
  size_t pix[2];
#pragma unroll
  for (int j = 0; j < 2; j++) {
    int n = n0 + j * 16 + ln;
    int y = n >> 6, x = n & 63;
    pix[j] = ((size_t)(y + hd) * Wp + x + hd) * CIN;
  }
  f32x4 acc[2][2];
#pragma unroll
  for (int i = 0; i < 2; i++)
#pragma unroll
    for (int j = 0; j < 2; j++) acc[i][j] = (f32x4)(0.f);
  for (int ky = klo; ky < khi; ky++)
    for (int kx = klo; kx < khi; kx++) {
      const size_t toff = ((size_t)ky * Wp + kx) * dil * CIN;
      const unsigned short* wtap =
          wtall + ((size_t)kbr * 9 + ky * 3 + kx) * 64 * CIN;
      for (int kc = 0; kc < CIN / 32; kc++) {
        const int ko = kc * 32 + quad * 8;
        bf16x8 a[2], bv[2];
#pragma unroll
        for (int i = 0; i < 2; i++)
          a[i] = *(const bf16x8*)(wtap + (size_t)(cw + i * 16 + ln) * CIN + ko);
#pragma unroll
        for (int j = 0; j < 2; j++)
          bv[j] = *(const bf16x8*)(inb + pix[j] + toff + ko);
#pragma unroll
        for (int i = 0; i < 2; i++)
#pragma unroll
          for (int j = 0; j < 2; j++)
            acc[i][j] = __builtin_amdgcn_mfma_f32_16x16x32_bf16(a[i], bv[j], acc[i][j], 0, 0, 0);
      }
    }
#pragma unroll
  for (int i = 0; i < 2; i++)
#pragma unroll
    for (int j = 0; j < 2; j++)
#pragma unroll
      for (int r = 0; r < 4; r++)
        br[((size_t)bb * 64 + cw + i * 16 + quad * 4 + r) * N + n0 + j * 16 + ln] =
            acc[i][j][r];
}

// ---------------- BN training-mode stats -> per-channel scale/shift ----------------
__global__ __launch_bounds__(256) void bn_stats_kernel(
    const float* __restrict__ t, const float* __restrict__ gamma,
    const float* __restrict__ beta, float* __restrict__ ss, int C) {
  const int c = blockIdx.x;
  float s = 0.f, s2 = 0.f;
  for (int b = 0; b < Bn; b++) {
    const float* p = t + ((size_t)(b * C + c)) * N;
    for (int i = threadIdx.x; i < N; i += 256) {
      float v = p[i];
      s += v; s2 = fmaf(v, v, s2);
    }
  }
  for (int off = 32; off; off >>= 1) {
    s += __shfl_down(s, off, 64);
    s2 += __shfl_down(s2, off, 64);
  }
  __shared__ float rs[4], rs2[4];
  const int wid = threadIdx.x >> 6, lane = threadIdx.x & 63;
  if (lane == 0) { rs[wid] = s; rs2[wid] = s2; }
  __syncthreads();
  if (threadIdx.x == 0) {
    float S1 = rs[0] + rs[1] + rs[2] + rs[3];
    float S2 = rs2[0] + rs2[1] + rs2[2] + rs2[3];
    const float cnt = (float)(Bn * N);
    float mean = S1 / cnt;
    float var = S2 / cnt - mean * mean;
    float sc = gamma[c] * rsqrtf(var + 1e-5f);
    ss[2 * c] = sc;
    ss[2 * c + 1] = beta[c] - mean * sc;
  }
}

// ---------------- BN+ReLU -> NHWC bf16 padded buffer (C=256) ----------------
__global__ __launch_bounds__(256) void bn_norm_pad_kernel(
    const float* __restrict__ t, const float* __restrict__ ss,
    unsigned short* __restrict__ outp, int Wp, int halo) {
  int i = blockIdx.x * 256 + threadIdx.x;
  int n = i & 4095, cg = (i >> 12) & 63, b = i >> 18;
  int c0 = cg * 4;
  ushort4 pk;
  float v0 = fmaxf(fmaf(t[((size_t)(b * 256 + c0 + 0)) * N + n], ss[2 * (c0 + 0)], ss[2 * (c0 + 0) + 1]), 0.f);
  float v1 = fmaxf(fmaf(t[((size_t)(b * 256 + c0 + 1)) * N + n], ss[2 * (c0 + 1)], ss[2 * (c0 + 1) + 1]), 0.f);
  float v2 = fmaxf(fmaf(t[((size_t)(b * 256 + c0 + 2)) * N + n], ss[2 * (c0 + 2)], ss[2 * (c0 + 2) + 1]), 0.f);
  float v3 = fmaxf(fmaf(t[((size_t)(b * 256 + c0 + 3)) * N + n], ss[2 * (c0 + 3)], ss[2 * (c0 + 3) + 1]), 0.f);
  pk.x = bfc(v0); pk.y = bfc(v1); pk.z = bfc(v2); pk.w = bfc(v3);
  int y = n >> 6, x = n & 63;
  *(ushort4*)(outp + (((size_t)b * Wp + y + halo) * Wp + x + halo) * 256 + c0) = pk;
}

// normalize+ReLU in place (ASPP branch outputs, fp32)
__global__ __launch_bounds__(256) void bn_norm_kernel(
    float* __restrict__ t, const float* __restrict__ ss, int Cmask) {
  int i = blockIdx.x * 256 + threadIdx.x;
  int c = (i >> 12) & Cmask;
  t[i] = fmaxf(fmaf(t[i], ss[2 * c], ss[2 * c + 1]), 0.f);
}

// ---------------- q/k/v 1x1 convs -> bf16 MFMA-layout buffers ----------------
__global__ __launch_bounds__(256) void qkv_kernel(
    const float* __restrict__ br,
    const float* __restrict__ wq, const float* __restrict__ bq,
    const float* __restrict__ wk, const float* __restrict__ bk,
    const float* __restrict__ wv, const float* __restrict__ bvb,
    unsigned short* __restrict__ qTo, unsigned short* __restrict__ kTo,
    unsigned short* __restrict__ vbo) {
  const int bb = blockIdx.z;
  const int p = blockIdx.y >> 2, dg = blockIdx.y & 3;
  const float* w  = p == 0 ? wq : (p == 1 ? wk : wv);
  const float* bi = p == 0 ? bq : (p == 1 ? bk : bvb);
  __shared__ float wl[64 * 16];
  const int d0b = dg * 16;
  for (int i = threadIdx.x; i < 64 * 16; i += 256)
    wl[i] = w[(size_t)(d0b + (i & 15)) * 64 + (i >> 4)];
  __syncthreads();
  const int tn = threadIdx.x & 63, td = threadIdx.x >> 6;
  const int n0 = blockIdx.x * 256 + tn * 4;
  const int d0 = d0b + td * 4;
  const float* inb = br + (size_t)bb * 64 * N;
  float4 acc[4];
#pragma unroll
  for (int j = 0; j < 4; j++) {
    float bvv = bi[d0 + j];
    acc[j] = make_float4(bvv, bvv, bvv, bvv);
  }
  for (int ci = 0; ci < 64; ci++) {
    float4 u = *(const float4*)(inb + (size_t)ci * N + n0);
    float4 wv4 = *(const float4*)(wl + ci * 16 + td * 4);
    fma4(acc[0], wv4.x, u); fma4(acc[1], wv4.y, u);
    fma4(acc[2], wv4.z, u); fma4(acc[3], wv4.w, u);
  }
  const size_t slab = (size_t)bb * N * 64;
  if (p < 2) {
    unsigned short* o = (p == 0 ? qTo : kTo) + slab;
#pragma unroll
    for (int nn = 0; nn < 4; nn++) {
      ushort4 pk;
      pk.x = bfc(((const float*)&acc[0])[nn]);
      pk.y = bfc(((const float*)&acc[1])[nn]);
      pk.z = bfc(((const float*)&acc[2])[nn]);
      pk.w = bfc(((const float*)&acc[3])[nn]);
      *(ushort4*)(o + (size_t)(n0 + nn) * 64 + d0) = pk;
    }
  } else {
    unsigned short* o = vbo + slab;
#pragma unroll
    for (int j = 0; j < 4; j++) {
      ushort4 pk;
      pk.x = bfc(acc[j].x); pk.y = bfc(acc[j].y);
      pk.z = bfc(acc[j].z); pk.w = bfc(acc[j].w);
      *(ushort4*)(o + (size_t)(d0 + j) * N + n0) = pk;
    }
  }
}

// ---------------- posT[n][d] = rel_w[d][h] + rel_h[d][w], bf16 ----------------
__global__ __launch_bounds__(256) void posT_kernel(
    const float* __restrict__ rel_h, const float* __restrict__ rel_w,
    unsigned short* __restrict__ posT) {
  int i = blockIdx.x * 256 + threadIdx.x;  // 65536
  int n = i >> 4, dq = (i & 15) * 4;
  int h = n >> 6, wc = n & 63;
  ushort4 pk;
  pk.x = bfc(rel_w[(dq + 0) * 64 + h] + rel_h[(dq + 0) * 64 + wc]);
  pk.y = bfc(rel_w[(dq + 1) * 64 + h] + rel_h[(dq + 1) * 64 + wc]);
  pk.z = bfc(rel_w[(dq + 2) * 64 + h] + rel_h[(dq + 2) * 64 + wc]);
  pk.w = bfc(rel_w[(dq + 3) * 64 + h] + rel_h[(dq + 3) * 64 + wc]);
  *(ushort4*)(posT + (size_t)n * 64 + dq) = pk;
}

// ---------------- fused flash attention ----------------
// grid (64 m-tiles, 16 pairs); 4 waves, each owns 16 m-rows. No __syncthreads.
// S^T formulation: St[c][m] = q[m]·k[c] + pos[m]·q[c]; C-layout puts m=lane&15
// so online-softmax state is scalar per lane. P^T staged via per-wave LDS into
// PV B-fragments; V A-frags register-direct from vb[d][N].
__global__ __launch_bounds__(256, 4) void flash_kernel(
    const unsigned short* __restrict__ qT, const unsigned short* __restrict__ kT,
    const unsigned short* __restrict__ posT, const unsigned short* __restrict__ vb,
    float* __restrict__ out) {
  const int bb = blockIdx.y, kbr = bb >> 2, b = bb & 3;
  const size_t slab = (size_t)bb * N * 64;
  const unsigned short* qTs = qT + slab;
  const unsigned short* kTs = kT + slab;
  const unsigned short* vbs = vb + slab;
  const int w = threadIdx.x >> 6, lane = threadIdx.x & 63;
  const int ln = lane & 15, quad = lane >> 4;
  const int m0 = blockIdx.x * 64 + w * 16;  // this wave's 16 m-rows
  __shared__ __align__(16) unsigned short pl[4][16][80];  // per-wave P^T [m][c]

  // B-side (m rows) fragments, loaded once: s<2 -> q rows, s>=2 -> pos rows
  bf16x8 bq[4];
#pragma unroll
  for (int s = 0; s < 4; s++) {
    const unsigned short* src = (s < 2) ? qTs : posT;
    bq[s] = *(const bf16x8*)(src + (size_t)(m0 + ln) * 64 + (s & 1) * 32 + quad * 8);
  }

  float m_run = -3.0e38f, l_run = 0.f;
  f32x4 o_acc[4];
#pragma unroll
  for (int dt = 0; dt < 4; dt++) o_acc[dt] = (f32x4)(0.f);

  for (int c0 = 0; c0 < N; c0 += 64) {
    // ---- S^T tiles: st[jt] = St[c = c0+jt*16+quad*4+r][m = m0+ln]
    f32x4 st[4];
#pragma unroll
    for (int jt = 0; jt < 4; jt++) st[jt] = (f32x4)(0.f);
#pragma unroll
    for (int s = 0; s < 4; s++) {
      const unsigned short* asrc = (s < 2) ? kTs : qTs;  // c-side rows
      const int koff = (s & 1) * 32 + quad * 8;
#pragma unroll
      for (int jt = 0; jt < 4; jt++) {
        bf16x8 a = *(const bf16x8*)(asrc + (size_t)(c0 + jt * 16 + ln) * 64 + koff);
        st[jt] = __builtin_amdgcn_mfma_f32_16x16x32_bf16(a, bq[s], st[jt], 0, 0, 0);
      }
    }
    // ---- online softmax (row m = ln is per-lane scalar state)
    float mx = -3.0e38f;
#pragma unroll
    for (int jt = 0; jt < 4; jt++)
#pragma unroll
      for (int r = 0; r < 4; r++) mx = fmaxf(mx, st[jt][r]);
    mx = fmaxf(mx, __shfl_xor(mx, 16, 64));
    mx = fmaxf(mx, __shfl_xor(mx, 32, 64));
    const float m_new = fmaxf(m_run, mx);
    const float alpha = __expf(m_run - m_new);
    float psum = 0.f;
#pragma unroll
    for (int jt = 0; jt < 4; jt++) {
      float e0 = __expf(st[jt][0] - m_new);
      float e1 = __expf(st[jt][1] - m_new);
      float e2 = __expf(st[jt][2] - m_new);
      float e3 = __expf(st[jt][3] - m_new);
      psum += (e0 + e1) + (e2 + e3);
      unsigned lo = (unsigned)bfc(e0) | ((unsigned)bfc(e1) << 16);
      unsigned hi = (unsigned)bfc(e2) | ((unsigned)bfc(e3) << 16);
      *(uint2*)(&pl[w][ln][jt * 16 + quad * 4]) = make_uint2(lo, hi);
    }
    psum += __shfl_xor(psum, 16, 64);
    psum += __shfl_xor(psum, 32, 64);
    l_run = l_run * alpha + psum;
    m_run = m_new;
#pragma unroll
    for (int dt = 0; dt < 4; dt++)
#pragma unroll
      for (int r = 0; r < 4; r++) o_acc[dt][r] *= alpha;
    // ---- PV: O[d][m] += V[d][c] * P[c][m]  (same-wave LDS round trip)
#pragma unroll
    for (int t = 0; t < 2; t++) {
      bf16x8 bp = *(const bf16x8*)(&pl[w][ln][t * 32 + quad * 8]);
#pragma unroll
      for (int dt = 0; dt < 4; dt++) {
        bf16x8 av = *(const bf16x8*)(vbs + (size_t)(dt * 16 + ln) * N + c0 + t * 32 + quad * 8);
        o_acc[dt] = __builtin_amdgcn_mfma_f32_16x16x32_bf16(av, bp, o_acc[dt], 0, 0, 0);
      }
    }
  }
  const float inv = 1.0f / l_run;
#pragma unroll
  for (int dt = 0; dt < 4; dt++)
#pragma unroll
    for (int r = 0; r < 4; r++) {
      int d = dt * 16 + quad * 4 + r;
      out[((size_t)(b * 256 + kbr * 64 + d)) * N + m0 + ln] = o_acc[dt][r] * inv;
    }
}

extern "C" void kernel_launch(void* const* d_in, const int* in_sizes, int n_in,
                              void* d_out, int out_size, void* d_ws, size_t ws_size,
                              hipStream_t stream) {
  const float* x      = (const float*)d_in[0];
  const float* dc_w1  = (const float*)d_in[1];
  const float* dc_g1  = (const float*)d_in[3];
  const float* dc_be1 = (const float*)d_in[4];
  const float* dc_w2  = (const float*)d_in[5];
  const float* dc_g2  = (const float*)d_in[7];
  const float* dc_be2 = (const float*)d_in[8];
  const float* aspp_w[4] = {(const float*)d_in[9],  (const float*)d_in[12],
                            (const float*)d_in[15], (const float*)d_in[18]};
  const float* aspp_g[4] = {(const float*)d_in[10], (const float*)d_in[13],
                            (const float*)d_in[16], (const float*)d_in[19]};
  const float* aspp_b[4] = {(const float*)d_in[11], (const float*)d_in[14],
                            (const float*)d_in[17], (const float*)d_in[20]};
  const float* wq = (const float*)d_in[21];
  const float* bq = (const float*)d_in[22];
  const float* wk = (const float*)d_in[23];
  const float* bk = (const float*)d_in[24];
  const float* wv = (const float*)d_in[25];
  const float* bv = (const float*)d_in[26];
  const float* rel_h = (const float*)d_in[27];
  const float* rel_w = (const float*)d_in[28];
  float* out = (float*)d_out;

  float* ws = (float*)d_ws;
  size_t off = 0;
  auto alloc = [&](size_t nf) { float* p = ws + off; off += nf; return p; };
  unsigned short* Pp1 = (unsigned short*)alloc((size_t)4 * 66 * 66 * 128 / 2 + 64);
  unsigned short* Pp2 = (unsigned short*)alloc((size_t)4 * 66 * 66 * 256 / 2 + 64);
  unsigned short* Pp3 = (unsigned short*)alloc((size_t)4 * 82 * 82 * 256 / 2 + 64);
  float* t1   = alloc((size_t)4 * 256 * N);
  float* br   = alloc((size_t)4 * 4 * 64 * N);
  float* st1  = alloc(512);
  float* st2  = alloc(512);
  float* sta  = alloc(512);
  unsigned short* qT    = (unsigned short*)alloc((size_t)16 * N * 64 / 2);
  unsigned short* kT    = (unsigned short*)alloc((size_t)16 * N * 64 / 2);
  unsigned short* vb    = (unsigned short*)alloc((size_t)16 * N * 64 / 2);
  unsigned short* posT  = (unsigned short*)alloc((size_t)N * 64 / 2);
  unsigned short* wt1   = (unsigned short*)alloc((size_t)9 * 256 * 128 / 2);
  unsigned short* wt2   = (unsigned short*)alloc((size_t)9 * 256 * 256 / 2);
  unsigned short* wtbr  = (unsigned short*)alloc((size_t)4 * 9 * 64 * 256 / 2);

  hipMemsetAsync(Pp1, 0, (size_t)4 * 66 * 66 * 128 * 2, stream);
  hipMemsetAsync(Pp2, 0, (size_t)4 * 66 * 66 * 256 * 2, stream);
  hipMemsetAsync(Pp3, 0, (size_t)4 * 82 * 82 * 256 * 2, stream);
  hipMemsetAsync(wtbr, 0, (size_t)4 * 9 * 64 * 256 * 2, stream);

  // weight prep
  wtr_kernel<<<(9 * 256 * 128) / 256, 256, 0, stream>>>(dc_w1, wt1, 256, 128, 9);
  wtr_kernel<<<(9 * 256 * 256) / 256, 256, 0, stream>>>(dc_w2, wt2, 256, 256, 9);
  wtr_kernel<<<(64 * 256) / 256, 256, 0, stream>>>(
      aspp_w[0], wtbr + (size_t)4 * 64 * 256, 64, 256, 1);
  for (int kbr = 1; kbr < 4; kbr++)
    wtr_kernel<<<(9 * 64 * 256) / 256, 256, 0, stream>>>(
        aspp_w[kbr], wtbr + (size_t)kbr * 9 * 64 * 256, 64, 256, 9);

  pool_kernel<<<2048, 256, 0, stream>>>(x, Pp1);

  dcconv_kernel<128><<<dim3(32, 4, 4), 256, 0, stream>>>(Pp1, wt1, t1);
  bn_stats_kernel<<<256, 256, 0, stream>>>(t1, dc_g1, dc_be1, st1, 256);
  bn_norm_pad_kernel<<<4096, 256, 0, stream>>>(t1, st1, Pp2, 66, 1);
  dcconv_kernel<256><<<dim3(32, 4, 4), 256, 0, stream>>>(Pp2, wt2, t1);
  bn_stats_kernel<<<256, 256, 0, stream>>>(t1, dc_g2, dc_be2, st2, 256);
  bn_norm_pad_kernel<<<4096, 256, 0, stream>>>(t1, st2, Pp3, 82, 9);

  branch_kernel<<<dim3(64, 16), 256, 0, stream>>>(Pp3, wtbr, br);
  for (int kbr = 0; kbr < 4; kbr++) {
    bn_stats_kernel<<<64, 256, 0, stream>>>(br + (size_t)kbr * 1048576,
                                            aspp_g[kbr], aspp_b[kbr],
                                            sta + kbr * 128, 64);
    bn_norm_kernel<<<4096, 256, 0, stream>>>(br + (size_t)kbr * 1048576,
                                             sta + kbr * 128, 63);
  }

  qkv_kernel<<<dim3(16, 12, 16), 256, 0, stream>>>(br, wq, bq, wk, bk, wv, bv,
                                                   qT, kT, vb);
  posT_kernel<<<256, 256, 0, stream>>>(rel_h, rel_w, posT);

  flash_kernel<<<dim3(64, 16), 256, 0, stream>>>(qT, kT, posT, vb, out);
}

// Round 5
// 1002.041 us; speedup vs baseline: 4.9791x; 1.2767x over previous
//
#include <hip/hip_runtime.h>
#include <math.h>

constexpr int Bn = 4;
constexpr int S  = 64;
constexpr int N  = 4096;  // S*S

#define DEV static __device__ __forceinline__

typedef __attribute__((ext_vector_type(8))) short bf16x8;
typedef __attribute__((ext_vector_type(4))) float f32x4;

DEV unsigned short bfc(float x) {  // f32 -> bf16 RNE
  unsigned u = __float_as_uint(x);
  unsigned r = (u + 0x7FFFu + ((u >> 16) & 1u)) >> 16;
  return (unsigned short)r;
}

DEV void fma4(float4& a, float s, const float4 u) {
  a.x = fmaf(s, u.x, a.x); a.y = fmaf(s, u.y, a.y);
  a.z = fmaf(s, u.z, a.z); a.w = fmaf(s, u.w, a.w);
}

// ---------------- weight transpose: src[Cout][Cin][T] f32 -> dst[T][Cout][Cin] bf16 ----
__global__ __launch_bounds__(256) void wtr_kernel(const float* __restrict__ src,
                                                  unsigned short* __restrict__ dst,
                                                  int Cout, int Cin, int T) {
  int i = blockIdx.x * 256 + threadIdx.x;
  int ci = i % Cin;
  int r  = i / Cin;
  int t  = r / Cout;
  int co = r - t * Cout;
  dst[i] = bfc(src[((size_t)co * Cin + ci) * T + t]);
}

// ---------------- maxpool 2x2 -> NHWC bf16 padded (halo=1) ----------------
__global__ __launch_bounds__(256) void pool_kernel(const float* __restrict__ x,
                                                   unsigned short* __restrict__ Pp1) {
  int i = blockIdx.x * 256 + threadIdx.x;  // 524288
  int xg = i & 15, y = (i >> 4) & 63, c = (i >> 10) & 127, b = i >> 17;
  const float* s = x + (((size_t)(b * 128 + c) * 128) + 2 * y) * 128 + 8 * xg;
  float4 u0 = *(const float4*)(s), u1 = *(const float4*)(s + 4);
  float4 u2 = *(const float4*)(s + 128), u3 = *(const float4*)(s + 132);
  float m0 = fmaxf(fmaxf(u0.x, u0.y), fmaxf(u2.x, u2.y));
  float m1 = fmaxf(fmaxf(u0.z, u0.w), fmaxf(u2.z, u2.w));
  float m2 = fmaxf(fmaxf(u1.x, u1.y), fmaxf(u3.x, u3.y));
  float m3 = fmaxf(fmaxf(u1.z, u1.w), fmaxf(u3.z, u3.w));
  unsigned short* d = Pp1 + (((size_t)b * 66 + y + 1) * 66 + xg * 4 + 1) * 128 + c;
  d[0] = bfc(m0); d[128] = bfc(m1); d[256] = bfc(m2); d[384] = bfc(m3);
}

// ---------------- dc conv: implicit GEMM, 9 taps, Cout=256 ----------------
template <int CIN>
__global__ __launch_bounds__(256) void dcconv_kernel(
    const unsigned short* __restrict__ in, const unsigned short* __restrict__ wt,
    float* __restrict__ out) {
  const int Wp = 66;
  const int w = threadIdx.x >> 6, lane = threadIdx.x & 63;
  const int ln = lane & 15, quad = lane >> 4;
  const int b = blockIdx.z, co0 = blockIdx.y * 64;
  const int n0 = blockIdx.x * 128 + w * 32;
  const unsigned short* inb = in + (size_t)b * Wp * Wp * CIN;
  size_t pix[2];
#pragma unroll
  for (int j = 0; j < 2; j++) {
    int n = n0 + j * 16 + ln;
    int y = n >> 6, x = n & 63;
    pix[j] = ((size_t)y * Wp + x) * CIN;
  }
  f32x4 acc[4][2];
#pragma unroll
  for (int i = 0; i < 4; i++)
#pragma unroll
    for (int j = 0; j < 2; j++) acc[i][j] = (f32x4)(0.f);
#pragma unroll
  for (int ky = 0; ky < 3; ky++)
#pragma unroll
    for (int kx = 0; kx < 3; kx++) {
      const size_t toff = ((size_t)ky * Wp + kx) * CIN;
      const unsigned short* wtap = wt + (size_t)(ky * 3 + kx) * 256 * CIN;
      for (int kc = 0; kc < CIN / 32; kc++) {
        const int ko = kc * 32 + quad * 8;
        bf16x8 a[4], bb[2];
#pragma unroll
        for (int i = 0; i < 4; i++)
          a[i] = *(const bf16x8*)(wtap + (size_t)(co0 + i * 16 + ln) * CIN + ko);
#pragma unroll
        for (int j = 0; j < 2; j++)
          bb[j] = *(const bf16x8*)(inb + pix[j] + toff + ko);
#pragma unroll
        for (int i = 0; i < 4; i++)
#pragma unroll
          for (int j = 0; j < 2; j++)
            acc[i][j] = __builtin_amdgcn_mfma_f32_16x16x32_bf16(a[i], bb[j], acc[i][j], 0, 0, 0);
      }
    }
#pragma unroll
  for (int i = 0; i < 4; i++)
#pragma unroll
    for (int j = 0; j < 2; j++)
#pragma unroll
      for (int r = 0; r < 4; r++)
        out[((size_t)(b * 256 + co0 + i * 16 + quad * 4 + r)) * N + n0 + j * 16 + ln] =
            acc[i][j][r];
}

// ---------------- all 4 ASPP branches, implicit GEMM on Pp3 (halo=9) ----------------
__global__ __launch_bounds__(256) void branch_kernel(
    const unsigned short* __restrict__ in, const unsigned short* __restrict__ wtall,
    float* __restrict__ br) {
  const int Wp = 82, halo = 9, CIN = 256;
  const int w = threadIdx.x >> 6, lane = threadIdx.x & 63;
  const int ln = lane & 15, quad = lane >> 4;
  const int bb = blockIdx.y;
  const int kbr = bb >> 2, b = bb & 3;
  const int dil = (kbr == 0) ? 1 : 3 * kbr;
  const int klo = (kbr == 0) ? 1 : 0, khi = (kbr == 0) ? 2 : 3;
  const int hd = halo - dil;
  const int cw = (w & 1) * 32, nw = (w >> 1) * 32;
  const int n0 = blockIdx.x * 64 + nw;
  const unsigned short* inb = in + (size_t)b * Wp * Wp * CIN;
  size_t pix[2];
#pragma unroll
  for (int j = 0; j < 2; j++) {
    int n = n0 + j * 16 + ln;
    int y = n >> 6, x = n & 63;
    pix[j] = ((size_t)(y + hd) * Wp + x + hd) * CIN;
  }
  f32x4 acc[2][2];
#pragma unroll
  for (int i = 0; i < 2; i++)
#pragma unroll
    for (int j = 0; j < 2; j++) acc[i][j] = (f32x4)(0.f);
  for (int ky = klo; ky < khi; ky++)
    for (int kx = klo; kx < khi; kx++) {
      const size_t toff = ((size_t)ky * Wp + kx) * dil * CIN;
      const unsigned short* wtap =
          wtall + ((size_t)kbr * 9 + ky * 3 + kx) * 64 * CIN;
      for (int kc = 0; kc < CIN / 32; kc++) {
        const int ko = kc * 32 + quad * 8;
        bf16x8 a[2], bv[2];
#pragma unroll
        for (int i = 0; i < 2; i++)
          a[i] = *(const bf16x8*)(wtap + (size_t)(cw + i * 16 + ln) * CIN + ko);
#pragma unroll
        for (int j = 0; j < 2; j++)
          bv[j] = *(const bf16x8*)(inb + pix[j] + toff + ko);
#pragma unroll
        for (int i = 0; i < 2; i++)
#pragma unroll
          for (int j = 0; j < 2; j++)
            acc[i][j] = __builtin_amdgcn_mfma_f32_16x16x32_bf16(a[i], bv[j], acc[i][j], 0, 0, 0);
      }
    }
#pragma unroll
  for (int i = 0; i < 2; i++)
#pragma unroll
    for (int j = 0; j < 2; j++)
#pragma unroll
      for (int r = 0; r < 4; r++)
        br[((size_t)bb * 64 + cw + i * 16 + quad * 4 + r) * N + n0 + j * 16 + ln] =
            acc[i][j][r];
}

// ---------------- BN training-mode stats -> per-channel scale/shift ----------------
__global__ __launch_bounds__(256) void bn_stats_kernel(
    const float* __restrict__ t, const float* __restrict__ gamma,
    const float* __restrict__ beta, float* __restrict__ ss, int C) {
  const int c = blockIdx.x;
  float s = 0.f, s2 = 0.f;
  for (int b = 0; b < Bn; b++) {
    const float* p = t + ((size_t)(b * C + c)) * N;
    for (int i = threadIdx.x; i < N; i += 256) {
      float v = p[i];
      s += v; s2 = fmaf(v, v, s2);
    }
  }
  for (int off = 32; off; off >>= 1) {
    s += __shfl_down(s, off, 64);
    s2 += __shfl_down(s2, off, 64);
  }
  __shared__ float rs[4], rs2[4];
  const int wid = threadIdx.x >> 6, lane = threadIdx.x & 63;
  if (lane == 0) { rs[wid] = s; rs2[wid] = s2; }
  __syncthreads();
  if (threadIdx.x == 0) {
    float S1 = rs[0] + rs[1] + rs[2] + rs[3];
    float S2 = rs2[0] + rs2[1] + rs2[2] + rs2[3];
    const float cnt = (float)(Bn * N);
    float mean = S1 / cnt;
    float var = S2 / cnt - mean * mean;
    float sc = gamma[c] * rsqrtf(var + 1e-5f);
    ss[2 * c] = sc;
    ss[2 * c + 1] = beta[c] - mean * sc;
  }
}

// ---------------- BN+ReLU -> NHWC bf16 padded buffer (C=256) ----------------
__global__ __launch_bounds__(256) void bn_norm_pad_kernel(
    const float* __restrict__ t, const float* __restrict__ ss,
    unsigned short* __restrict__ outp, int Wp, int halo) {
  int i = blockIdx.x * 256 + threadIdx.x;
  int n = i & 4095, cg = (i >> 12) & 63, b = i >> 18;
  int c0 = cg * 4;
  ushort4 pk;
  float v0 = fmaxf(fmaf(t[((size_t)(b * 256 + c0 + 0)) * N + n], ss[2 * (c0 + 0)], ss[2 * (c0 + 0) + 1]), 0.f);
  float v1 = fmaxf(fmaf(t[((size_t)(b * 256 + c0 + 1)) * N + n], ss[2 * (c0 + 1)], ss[2 * (c0 + 1) + 1]), 0.f);
  float v2 = fmaxf(fmaf(t[((size_t)(b * 256 + c0 + 2)) * N + n], ss[2 * (c0 + 2)], ss[2 * (c0 + 2) + 1]), 0.f);
  float v3 = fmaxf(fmaf(t[((size_t)(b * 256 + c0 + 3)) * N + n], ss[2 * (c0 + 3)], ss[2 * (c0 + 3) + 1]), 0.f);
  pk.x = bfc(v0); pk.y = bfc(v1); pk.z = bfc(v2); pk.w = bfc(v3);
  int y = n >> 6, x = n & 63;
  *(ushort4*)(outp + (((size_t)b * Wp + y + halo) * Wp + x + halo) * 256 + c0) = pk;
}

// normalize+ReLU in place (ASPP branch outputs, fp32)
__global__ __launch_bounds__(256) void bn_norm_kernel(
    float* __restrict__ t, const float* __restrict__ ss, int Cmask) {
  int i = blockIdx.x * 256 + threadIdx.x;
  int c = (i >> 12) & Cmask;
  t[i] = fmaxf(fmaf(t[i], ss[2 * c], ss[2 * c + 1]), 0.f);
}

// ---------------- q/k/v 1x1 convs -> bf16 MFMA-layout buffers ----------------
__global__ __launch_bounds__(256) void qkv_kernel(
    const float* __restrict__ br,
    const float* __restrict__ wq, const float* __restrict__ bq,
    const float* __restrict__ wk, const float* __restrict__ bk,
    const float* __restrict__ wv, const float* __restrict__ bvb,
    unsigned short* __restrict__ qTo, unsigned short* __restrict__ kTo,
    unsigned short* __restrict__ vbo) {
  const int bb = blockIdx.z;
  const int p = blockIdx.y >> 2, dg = blockIdx.y & 3;
  const float* w  = p == 0 ? wq : (p == 1 ? wk : wv);
  const float* bi = p == 0 ? bq : (p == 1 ? bk : bvb);
  __shared__ float wl[64 * 16];
  const int d0b = dg * 16;
  for (int i = threadIdx.x; i < 64 * 16; i += 256)
    wl[i] = w[(size_t)(d0b + (i & 15)) * 64 + (i >> 4)];
  __syncthreads();
  const int tn = threadIdx.x & 63, td = threadIdx.x >> 6;
  const int n0 = blockIdx.x * 256 + tn * 4;
  const int d0 = d0b + td * 4;
  const float* inb = br + (size_t)bb * 64 * N;
  float4 acc[4];
#pragma unroll
  for (int j = 0; j < 4; j++) {
    float bvv = bi[d0 + j];
    acc[j] = make_float4(bvv, bvv, bvv, bvv);
  }
  for (int ci = 0; ci < 64; ci++) {
    float4 u = *(const float4*)(inb + (size_t)ci * N + n0);
    float4 wv4 = *(const float4*)(wl + ci * 16 + td * 4);
    fma4(acc[0], wv4.x, u); fma4(acc[1], wv4.y, u);
    fma4(acc[2], wv4.z, u); fma4(acc[3], wv4.w, u);
  }
  const size_t slab = (size_t)bb * N * 64;
  if (p < 2) {
    unsigned short* o = (p == 0 ? qTo : kTo) + slab;
#pragma unroll
    for (int nn = 0; nn < 4; nn++) {
      ushort4 pk;
      pk.x = bfc(((const float*)&acc[0])[nn]);
      pk.y = bfc(((const float*)&acc[1])[nn]);
      pk.z = bfc(((const float*)&acc[2])[nn]);
      pk.w = bfc(((const float*)&acc[3])[nn]);
      *(ushort4*)(o + (size_t)(n0 + nn) * 64 + d0) = pk;
    }
  } else {
    unsigned short* o = vbo + slab;
#pragma unroll
    for (int j = 0; j < 4; j++) {
      ushort4 pk;
      pk.x = bfc(acc[j].x); pk.y = bfc(acc[j].y);
      pk.z = bfc(acc[j].z); pk.w = bfc(acc[j].w);
      *(ushort4*)(o + (size_t)(d0 + j) * N + n0) = pk;
    }
  }
}

// ---------------- posT[n][d] = rel_w[d][h] + rel_h[d][w], bf16 ----------------
__global__ __launch_bounds__(256) void posT_kernel(
    const float* __restrict__ rel_h, const float* __restrict__ rel_w,
    unsigned short* __restrict__ posT) {
  int i = blockIdx.x * 256 + threadIdx.x;  // 65536
  int n = i >> 4, dq = (i & 15) * 4;
  int h = n >> 6, wc = n & 63;
  ushort4 pk;
  pk.x = bfc(rel_w[(dq + 0) * 64 + h] + rel_h[(dq + 0) * 64 + wc]);
  pk.y = bfc(rel_w[(dq + 1) * 64 + h] + rel_h[(dq + 1) * 64 + wc]);
  pk.z = bfc(rel_w[(dq + 2) * 64 + h] + rel_h[(dq + 2) * 64 + wc]);
  pk.w = bfc(rel_w[(dq + 3) * 64 + h] + rel_h[(dq + 3) * 64 + wc]);
  *(ushort4*)(posT + (size_t)n * 64 + dq) = pk;
}

// ---------------- flash attention v2: split-c + 32 m per wave ----------------
// grid (32 m-tiles of 128, 16 pairs, 4 c-splits); 4 waves x 32 m. No barriers.
// Each block's c-range: [split*1024, split*1024+1024). Writes unnormalized
// o_part + (m_run,l_run) per split; combined by wcomb/comb kernels.
__global__ __launch_bounds__(256, 4) void flash2_kernel(
    const unsigned short* __restrict__ qT, const unsigned short* __restrict__ kT,
    const unsigned short* __restrict__ posT, const unsigned short* __restrict__ vb,
    float* __restrict__ o_part, float* __restrict__ ml) {
  const int bb = blockIdx.y, split = blockIdx.z;
  const size_t slab = (size_t)bb * N * 64;
  const unsigned short* qTs = qT + slab;
  const unsigned short* kTs = kT + slab;
  const unsigned short* vbs = vb + slab;
  const int w = threadIdx.x >> 6, lane = threadIdx.x & 63;
  const int ln = lane & 15, quad = lane >> 4;
  const int m0 = blockIdx.x * 128 + w * 32;  // wave's 32 m-rows (2 frags)
  __shared__ __align__(16) unsigned short pl[4][2][16][72];  // P^T, pad 72 (2-way=free)

  // m-side B fragments: s<2 -> q rows, s>=2 -> pos rows (loaded once)
  bf16x8 bq[4][2];
#pragma unroll
  for (int s = 0; s < 4; s++) {
    const unsigned short* src = (s < 2) ? qTs : posT;
#pragma unroll
    for (int mf = 0; mf < 2; mf++)
      bq[s][mf] = *(const bf16x8*)(src + (size_t)(m0 + mf * 16 + ln) * 64 +
                                   (s & 1) * 32 + quad * 8);
  }

  float m_run[2] = {-3.0e38f, -3.0e38f}, l_run[2] = {0.f, 0.f};
  f32x4 o_acc[4][2];
#pragma unroll
  for (int dt = 0; dt < 4; dt++)
#pragma unroll
    for (int mf = 0; mf < 2; mf++) o_acc[dt][mf] = (f32x4)(0.f);

  const int cbeg = split * 1024;
  for (int c0 = cbeg; c0 < cbeg + 1024; c0 += 64) {
    // ---- S^T: st[jt][mf][r] = St[c0+jt*16+quad*4+r][m0+mf*16+ln]
    f32x4 st[4][2];
#pragma unroll
    for (int jt = 0; jt < 4; jt++)
#pragma unroll
      for (int mf = 0; mf < 2; mf++) st[jt][mf] = (f32x4)(0.f);
#pragma unroll
    for (int s = 0; s < 4; s++) {
      const unsigned short* asrc = (s < 2) ? kTs : qTs;  // c-side rows
      const int koff = (s & 1) * 32 + quad * 8;
#pragma unroll
      for (int jt = 0; jt < 4; jt++) {
        bf16x8 a = *(const bf16x8*)(asrc + (size_t)(c0 + jt * 16 + ln) * 64 + koff);
#pragma unroll
        for (int mf = 0; mf < 2; mf++)
          st[jt][mf] = __builtin_amdgcn_mfma_f32_16x16x32_bf16(a, bq[s][mf], st[jt][mf], 0, 0, 0);
      }
    }
    // ---- online softmax per mf (row state scalar per lane)
#pragma unroll
    for (int mf = 0; mf < 2; mf++) {
      float mx = -3.0e38f;
#pragma unroll
      for (int jt = 0; jt < 4; jt++)
#pragma unroll
        for (int r = 0; r < 4; r++) mx = fmaxf(mx, st[jt][mf][r]);
      mx = fmaxf(mx, __shfl_xor(mx, 16, 64));
      mx = fmaxf(mx, __shfl_xor(mx, 32, 64));
      const float m_new = fmaxf(m_run[mf], mx);
      const float alpha = __expf(m_run[mf] - m_new);
      float psum = 0.f;
#pragma unroll
      for (int jt = 0; jt < 4; jt++) {
        float e0 = __expf(st[jt][mf][0] - m_new);
        float e1 = __expf(st[jt][mf][1] - m_new);
        float e2 = __expf(st[jt][mf][2] - m_new);
        float e3 = __expf(st[jt][mf][3] - m_new);
        psum += (e0 + e1) + (e2 + e3);
        unsigned lo = (unsigned)bfc(e0) | ((unsigned)bfc(e1) << 16);
        unsigned hi = (unsigned)bfc(e2) | ((unsigned)bfc(e3) << 16);
        *(uint2*)(&pl[w][mf][ln][jt * 16 + quad * 4]) = make_uint2(lo, hi);
      }
      psum += __shfl_xor(psum, 16, 64);
      psum += __shfl_xor(psum, 32, 64);
      l_run[mf] = l_run[mf] * alpha + psum;
      m_run[mf] = m_new;
#pragma unroll
      for (int dt = 0; dt < 4; dt++)
#pragma unroll
        for (int r = 0; r < 4; r++) o_acc[dt][mf][r] *= alpha;
    }
    // ---- PV: O[d][m] += V[d][c] * P[c][m]; V frags reused across both mf
#pragma unroll
    for (int t = 0; t < 2; t++) {
      bf16x8 av[4];
#pragma unroll
      for (int dt = 0; dt < 4; dt++)
        av[dt] = *(const bf16x8*)(vbs + (size_t)(dt * 16 + ln) * N + c0 + t * 32 + quad * 8);
#pragma unroll
      for (int mf = 0; mf < 2; mf++) {
        bf16x8 bp = *(const bf16x8*)(&pl[w][mf][ln][t * 32 + quad * 8]);
#pragma unroll
        for (int dt = 0; dt < 4; dt++)
          o_acc[dt][mf] = __builtin_amdgcn_mfma_f32_16x16x32_bf16(av[dt], bp, o_acc[dt][mf], 0, 0, 0);
      }
    }
  }
  // ---- epilogue: unnormalized partials
  float* ob = o_part + ((size_t)(split * 16 + bb) * 64) * N;
#pragma unroll
  for (int dt = 0; dt < 4; dt++)
#pragma unroll
    for (int mf = 0; mf < 2; mf++)
#pragma unroll
      for (int r = 0; r < 4; r++) {
        int d = dt * 16 + quad * 4 + r;
        ob[(size_t)d * N + m0 + mf * 16 + ln] = o_acc[dt][mf][r];
      }
  if (quad == 0) {
#pragma unroll
    for (int mf = 0; mf < 2; mf++) {
      int m = m0 + mf * 16 + ln;
      ml[((size_t)(split * 16 + bb) * 2 + 0) * N + m] = m_run[mf];
      ml[((size_t)(split * 16 + bb) * 2 + 1) * N + m] = l_run[mf];
    }
  }
}

// ---------------- combine weights: wcb[s][bb][m] = exp(m_s-M)/sum_s exp(m_s-M)*l_s ----
__global__ __launch_bounds__(256) void wcomb_kernel(const float* __restrict__ ml,
                                                    float* __restrict__ wcb) {
  int i = blockIdx.x * 256 + threadIdx.x;  // 16*4096
  int m = i & 4095, bb = i >> 12;
  float mv[4], lv[4];
#pragma unroll
  for (int s = 0; s < 4; s++) {
    mv[s] = ml[((size_t)(s * 16 + bb) * 2 + 0) * N + m];
    lv[s] = ml[((size_t)(s * 16 + bb) * 2 + 1) * N + m];
  }
  float M = fmaxf(fmaxf(mv[0], mv[1]), fmaxf(mv[2], mv[3]));
  float wsc[4], denom = 0.f;
#pragma unroll
  for (int s = 0; s < 4; s++) {
    wsc[s] = __expf(mv[s] - M);
    denom = fmaf(wsc[s], lv[s], denom);
  }
  float inv = 1.0f / denom;
#pragma unroll
  for (int s = 0; s < 4; s++)
    wcb[(size_t)(s * 16 + bb) * N + m] = wsc[s] * inv;
}

// ---------------- combine partials -> d_out ----------------
__global__ __launch_bounds__(256) void comb_kernel(const float* __restrict__ o_part,
                                                   const float* __restrict__ wcb,
                                                   float* __restrict__ out) {
  int i = blockIdx.x * 256 + threadIdx.x;  // 16*64*1024 float4 groups
  int m4 = i & 1023, d = (i >> 10) & 63, bb = i >> 16;
  int kbr = bb >> 2, b = bb & 3;
  float4 acc = make_float4(0.f, 0.f, 0.f, 0.f);
#pragma unroll
  for (int s = 0; s < 4; s++) {
    const float4 o = *(const float4*)(o_part + ((size_t)(s * 16 + bb) * 64 + d) * N + m4 * 4);
    const float4 wv = *(const float4*)(wcb + (size_t)(s * 16 + bb) * N + m4 * 4);
    acc.x = fmaf(o.x, wv.x, acc.x); acc.y = fmaf(o.y, wv.y, acc.y);
    acc.z = fmaf(o.z, wv.z, acc.z); acc.w = fmaf(o.w, wv.w, acc.w);
  }
  *(float4*)(out + ((size_t)(b * 256 + kbr * 64 + d)) * N + m4 * 4) = acc;
}

extern "C" void kernel_launch(void* const* d_in, const int* in_sizes, int n_in,
                              void* d_out, int out_size, void* d_ws, size_t ws_size,
                              hipStream_t stream) {
  const float* x      = (const float*)d_in[0];
  const float* dc_w1  = (const float*)d_in[1];
  const float* dc_g1  = (const float*)d_in[3];
  const float* dc_be1 = (const float*)d_in[4];
  const float* dc_w2  = (const float*)d_in[5];
  const float* dc_g2  = (const float*)d_in[7];
  const float* dc_be2 = (const float*)d_in[8];
  const float* aspp_w[4] = {(const float*)d_in[9],  (const float*)d_in[12],
                            (const float*)d_in[15], (const float*)d_in[18]};
  const float* aspp_g[4] = {(const float*)d_in[10], (const float*)d_in[13],
                            (const float*)d_in[16], (const float*)d_in[19]};
  const float* aspp_b[4] = {(const float*)d_in[11], (const float*)d_in[14],
                            (const float*)d_in[17], (const float*)d_in[20]};
  const float* wq = (const float*)d_in[21];
  const float* bq = (const float*)d_in[22];
  const float* wk = (const float*)d_in[23];
  const float* bk = (const float*)d_in[24];
  const float* wv = (const float*)d_in[25];
  const float* bv = (const float*)d_in[26];
  const float* rel_h = (const float*)d_in[27];
  const float* rel_w = (const float*)d_in[28];
  float* out = (float*)d_out;

  float* ws = (float*)d_ws;
  size_t off = 0;
  auto alloc = [&](size_t nf) { float* p = ws + off; off += nf; return p; };
  unsigned short* Pp1 = (unsigned short*)alloc((size_t)4 * 66 * 66 * 128 / 2 + 64);
  unsigned short* Pp2 = (unsigned short*)alloc((size_t)4 * 66 * 66 * 256 / 2 + 64);
  unsigned short* Pp3 = (unsigned short*)alloc((size_t)4 * 82 * 82 * 256 / 2 + 64);
  float* t1   = alloc((size_t)4 * 256 * N);
  float* br   = alloc((size_t)4 * 4 * 64 * N);
  float* st1  = alloc(512);
  float* st2  = alloc(512);
  float* sta  = alloc(512);
  unsigned short* qT    = (unsigned short*)alloc((size_t)16 * N * 64 / 2);
  unsigned short* kT    = (unsigned short*)alloc((size_t)16 * N * 64 / 2);
  unsigned short* vb    = (unsigned short*)alloc((size_t)16 * N * 64 / 2);
  unsigned short* posT  = (unsigned short*)alloc((size_t)N * 64 / 2);
  unsigned short* wt1   = (unsigned short*)alloc((size_t)9 * 256 * 128 / 2);
  unsigned short* wt2   = (unsigned short*)alloc((size_t)9 * 256 * 256 / 2);
  unsigned short* wtbr  = (unsigned short*)alloc((size_t)4 * 9 * 64 * 256 / 2);
  float* o_part = alloc((size_t)4 * 16 * 64 * N);  // 67 MB
  float* mlb    = alloc((size_t)4 * 16 * 2 * N);
  float* wcb    = alloc((size_t)4 * 16 * N);

  hipMemsetAsync(Pp1, 0, (size_t)4 * 66 * 66 * 128 * 2, stream);
  hipMemsetAsync(Pp2, 0, (size_t)4 * 66 * 66 * 256 * 2, stream);
  hipMemsetAsync(Pp3, 0, (size_t)4 * 82 * 82 * 256 * 2, stream);
  hipMemsetAsync(wtbr, 0, (size_t)4 * 9 * 64 * 256 * 2, stream);

  // weight prep
  wtr_kernel<<<(9 * 256 * 128) / 256, 256, 0, stream>>>(dc_w1, wt1, 256, 128, 9);
  wtr_kernel<<<(9 * 256 * 256) / 256, 256, 0, stream>>>(dc_w2, wt2, 256, 256, 9);
  wtr_kernel<<<(64 * 256) / 256, 256, 0, stream>>>(
      aspp_w[0], wtbr + (size_t)4 * 64 * 256, 64, 256, 1);
  for (int kbr = 1; kbr < 4; kbr++)
    wtr_kernel<<<(9 * 64 * 256) / 256, 256, 0, stream>>>(
        aspp_w[kbr], wtbr + (size_t)kbr * 9 * 64 * 256, 64, 256, 9);

  pool_kernel<<<2048, 256, 0, stream>>>(x, Pp1);

  dcconv_kernel<128><<<dim3(32, 4, 4), 256, 0, stream>>>(Pp1, wt1, t1);
  bn_stats_kernel<<<256, 256, 0, stream>>>(t1, dc_g1, dc_be1, st1, 256);
  bn_norm_pad_kernel<<<4096, 256, 0, stream>>>(t1, st1, Pp2, 66, 1);
  dcconv_kernel<256><<<dim3(32, 4, 4), 256, 0, stream>>>(Pp2, wt2, t1);
  bn_stats_kernel<<<256, 256, 0, stream>>>(t1, dc_g2, dc_be2, st2, 256);
  bn_norm_pad_kernel<<<4096, 256, 0, stream>>>(t1, st2, Pp3, 82, 9);

  branch_kernel<<<dim3(64, 16), 256, 0, stream>>>(Pp3, wtbr, br);
  for (int kbr = 0; kbr < 4; kbr++) {
    bn_stats_kernel<<<64, 256, 0, stream>>>(br + (size_t)kbr * 1048576,
                                            aspp_g[kbr], aspp_b[kbr],
                                            sta + kbr * 128, 64);
    bn_norm_kernel<<<4096, 256, 0, stream>>>(br + (size_t)kbr * 1048576,
                                             sta + kbr * 128, 63);
  }

  qkv_kernel<<<dim3(16, 12, 16), 256, 0, stream>>>(br, wq, bq, wk, bk, wv, bv,
                                                   qT, kT, vb);
  posT_kernel<<<256, 256, 0, stream>>>(rel_h, rel_w, posT);

  flash2_kernel<<<dim3(32, 16, 4), 256, 0, stream>>>(qT, kT, posT, vb, o_part, mlb);
  wcomb_kernel<<<256, 256, 0, stream>>>(mlb, wcb);
  comb_kernel<<<4096, 256, 0, stream>>>(o_part, wcb, out);
}

// Round 6
// 805.283 us; speedup vs baseline: 6.1956x; 1.2443x over previous
//
#include <hip/hip_runtime.h>
#include <math.h>

constexpr int Bn = 4;
constexpr int S  = 64;
constexpr int N  = 4096;  // S*S

#define DEV static __device__ __forceinline__

typedef __attribute__((ext_vector_type(8))) short bf16x8;
typedef __attribute__((ext_vector_type(4))) float f32x4;

DEV unsigned short bfc(float x) {  // f32 -> bf16 RNE
  unsigned u = __float_as_uint(x);
  unsigned r = (u + 0x7FFFu + ((u >> 16) & 1u)) >> 16;
  return (unsigned short)r;
}

DEV void fma4(float4& a, float s, const float4 u) {
  a.x = fmaf(s, u.x, a.x); a.y = fmaf(s, u.y, a.y);
  a.z = fmaf(s, u.z, a.z); a.w = fmaf(s, u.w, a.w);
}

// async global->LDS, 16B per lane; lds base must be wave-uniform (lane i lands at +i*16)
DEV void gload_lds16(const unsigned short* g, unsigned short* l) {
  __builtin_amdgcn_global_load_lds(
      (const __attribute__((address_space(1))) void*)g,
      (__attribute__((address_space(3))) void*)l, 16, 0, 0);
}

// ---------------- weight transpose: src[Cout][Cin][T] f32 -> dst[T][Cout][Cin] bf16 ----
__global__ __launch_bounds__(256) void wtr_kernel(const float* __restrict__ src,
                                                  unsigned short* __restrict__ dst,
                                                  int Cout, int Cin, int T) {
  int i = blockIdx.x * 256 + threadIdx.x;
  int ci = i % Cin;
  int r  = i / Cin;
  int t  = r / Cout;
  int co = r - t * Cout;
  dst[i] = bfc(src[((size_t)co * Cin + ci) * T + t]);
}

// ---------------- maxpool 2x2 -> NHWC bf16 padded (halo=1) ----------------
__global__ __launch_bounds__(256) void pool_kernel(const float* __restrict__ x,
                                                   unsigned short* __restrict__ Pp1) {
  int i = blockIdx.x * 256 + threadIdx.x;  // 524288
  int xg = i & 15, y = (i >> 4) & 63, c = (i >> 10) & 127, b = i >> 17;
  const float* s = x + (((size_t)(b * 128 + c) * 128) + 2 * y) * 128 + 8 * xg;
  float4 u0 = *(const float4*)(s), u1 = *(const float4*)(s + 4);
  float4 u2 = *(const float4*)(s + 128), u3 = *(const float4*)(s + 132);
  float m0 = fmaxf(fmaxf(u0.x, u0.y), fmaxf(u2.x, u2.y));
  float m1 = fmaxf(fmaxf(u0.z, u0.w), fmaxf(u2.z, u2.w));
  float m2 = fmaxf(fmaxf(u1.x, u1.y), fmaxf(u3.x, u3.y));
  float m3 = fmaxf(fmaxf(u1.z, u1.w), fmaxf(u3.z, u3.w));
  unsigned short* d = Pp1 + (((size_t)b * 66 + y + 1) * 66 + xg * 4 + 1) * 128 + c;
  d[0] = bfc(m0); d[128] = bfc(m1); d[256] = bfc(m2); d[384] = bfc(m3);
}

// ---------------- dc conv: implicit GEMM, ci-split x2 for occupancy ----------------
// z = b*2 + half; each half does CTOT/2 input channels; out[half] partial fp32.
template <int CTOT>
__global__ __launch_bounds__(256) void dcconv_kernel(
    const unsigned short* __restrict__ in, const unsigned short* __restrict__ wt,
    float* __restrict__ out) {
  const int Wp = 66, CSEG = CTOT / 2;
  const int w = threadIdx.x >> 6, lane = threadIdx.x & 63;
  const int ln = lane & 15, quad = lane >> 4;
  const int b = blockIdx.z >> 1, h = blockIdx.z & 1, co0 = blockIdx.y * 64;
  const int n0 = blockIdx.x * 128 + w * 32;
  const unsigned short* inb = in + (size_t)b * Wp * Wp * CTOT + h * CSEG;
  const unsigned short* wth = wt + h * CSEG;
  float* outh = out + (size_t)h * 4 * 256 * N;
  size_t pix[2];
#pragma unroll
  for (int j = 0; j < 2; j++) {
    int n = n0 + j * 16 + ln;
    int y = n >> 6, x = n & 63;
    pix[j] = ((size_t)y * Wp + x) * CTOT;
  }
  f32x4 acc[4][2];
#pragma unroll
  for (int i = 0; i < 4; i++)
#pragma unroll
    for (int j = 0; j < 2; j++) acc[i][j] = (f32x4)(0.f);
#pragma unroll
  for (int ky = 0; ky < 3; ky++)
#pragma unroll
    for (int kx = 0; kx < 3; kx++) {
      const size_t toff = ((size_t)ky * Wp + kx) * CTOT;
      const unsigned short* wtap = wth + (size_t)(ky * 3 + kx) * 256 * CTOT;
      for (int kc = 0; kc < CSEG / 32; kc++) {
        const int ko = kc * 32 + quad * 8;
        bf16x8 a[4], bb[2];
#pragma unroll
        for (int i = 0; i < 4; i++)
          a[i] = *(const bf16x8*)(wtap + (size_t)(co0 + i * 16 + ln) * CTOT + ko);
#pragma unroll
        for (int j = 0; j < 2; j++)
          bb[j] = *(const bf16x8*)(inb + pix[j] + toff + ko);
#pragma unroll
        for (int i = 0; i < 4; i++)
#pragma unroll
          for (int j = 0; j < 2; j++)
            acc[i][j] = __builtin_amdgcn_mfma_f32_16x16x32_bf16(a[i], bb[j], acc[i][j], 0, 0, 0);
      }
    }
#pragma unroll
  for (int i = 0; i < 4; i++)
#pragma unroll
    for (int j = 0; j < 2; j++)
#pragma unroll
      for (int r = 0; r < 4; r++)
        outh[((size_t)(b * 256 + co0 + i * 16 + quad * 4 + r)) * N + n0 + j * 16 + ln] =
            acc[i][j][r];
}

// ---------------- all 4 ASPP branches, implicit GEMM on Pp3 (halo=9) ----------------
__global__ __launch_bounds__(256) void branch_kernel(
    const unsigned short* __restrict__ in, const unsigned short* __restrict__ wtall,
    float* __restrict__ br) {
  const int Wp = 82, halo = 9, CIN = 256;
  const int w = threadIdx.x >> 6, lane = threadIdx.x & 63;
  const int ln = lane & 15, quad = lane >> 4;
  const int bb = blockIdx.y;
  const int kbr = bb >> 2, b = bb & 3;
  const int dil = (kbr == 0) ? 1 : 3 * kbr;
  const int klo = (kbr == 0) ? 1 : 0, khi = (kbr == 0) ? 2 : 3;
  const int hd = halo - dil;
  const int cw = (w & 1) * 32, nw = (w >> 1) * 32;
  const int n0 = blockIdx.x * 64 + nw;
  const unsigned short* inb = in + (size_t)b * Wp * Wp * CIN;
  size_t pix[2];
#pragma unroll
  for (int j = 0; j < 2; j++) {
    int n = n0 + j * 16 + ln;
    int y = n >> 6, x = n & 63;
    pix[j] = ((size_t)(y + hd) * Wp + x + hd) * CIN;
  }
  f32x4 acc[2][2];
#pragma unroll
  for (int i = 0; i < 2; i++)
#pragma unroll
    for (int j = 0; j < 2; j++) acc[i][j] = (f32x4)(0.f);
  for (int ky = klo; ky < khi; ky++)
    for (int kx = klo; kx < khi; kx++) {
      const size_t toff = ((size_t)ky * Wp + kx) * dil * CIN;
      const unsigned short* wtap =
          wtall + ((size_t)kbr * 9 + ky * 3 + kx) * 64 * CIN;
      for (int kc = 0; kc < CIN / 32; kc++) {
        const int ko = kc * 32 + quad * 8;
        bf16x8 a[2], bv[2];
#pragma unroll
        for (int i = 0; i < 2; i++)
          a[i] = *(const bf16x8*)(wtap + (size_t)(cw + i * 16 + ln) * CIN + ko);
#pragma unroll
        for (int j = 0; j < 2; j++)
          bv[j] = *(const bf16x8*)(inb + pix[j] + toff + ko);
#pragma unroll
        for (int i = 0; i < 2; i++)
#pragma unroll
          for (int j = 0; j < 2; j++)
            acc[i][j] = __builtin_amdgcn_mfma_f32_16x16x32_bf16(a[i], bv[j], acc[i][j], 0, 0, 0);
      }
    }
#pragma unroll
  for (int i = 0; i < 2; i++)
#pragma unroll
    for (int j = 0; j < 2; j++)
#pragma unroll
      for (int r = 0; r < 4; r++)
        br[((size_t)bb * 64 + cw + i * 16 + quad * 4 + r) * N + n0 + j * 16 + ln] =
            acc[i][j][r];
}

// ---------------- BN stats (single src, for branch outputs) ----------------
__global__ __launch_bounds__(256) void bn_stats_kernel(
    const float* __restrict__ t, const float* __restrict__ gamma,
    const float* __restrict__ beta, float* __restrict__ ss, int C) {
  const int c = blockIdx.x;
  float s = 0.f, s2 = 0.f;
  for (int b = 0; b < Bn; b++) {
    const float* p = t + ((size_t)(b * C + c)) * N;
    for (int i = threadIdx.x; i < N; i += 256) {
      float v = p[i];
      s += v; s2 = fmaf(v, v, s2);
    }
  }
  for (int off = 32; off; off >>= 1) {
    s += __shfl_down(s, off, 64);
    s2 += __shfl_down(s2, off, 64);
  }
  __shared__ float rs[4], rs2[4];
  const int wid = threadIdx.x >> 6, lane = threadIdx.x & 63;
  if (lane == 0) { rs[wid] = s; rs2[wid] = s2; }
  __syncthreads();
  if (threadIdx.x == 0) {
    float S1 = rs[0] + rs[1] + rs[2] + rs[3];
    float S2 = rs2[0] + rs2[1] + rs2[2] + rs2[3];
    const float cnt = (float)(Bn * N);
    float mean = S1 / cnt;
    float var = S2 / cnt - mean * mean;
    float sc = gamma[c] * rsqrtf(var + 1e-5f);
    ss[2 * c] = sc;
    ss[2 * c + 1] = beta[c] - mean * sc;
  }
}

// ---------------- BN stats over sum of two partial buffers (dc convs) ----------------
__global__ __launch_bounds__(256) void bn_stats2_kernel(
    const float* __restrict__ ta, const float* __restrict__ tb,
    const float* __restrict__ gamma, const float* __restrict__ beta,
    float* __restrict__ ss, int C) {
  const int c = blockIdx.x;
  float s = 0.f, s2 = 0.f;
  for (int b = 0; b < Bn; b++) {
    const size_t base = ((size_t)(b * C + c)) * N;
    for (int i = threadIdx.x; i < N; i += 256) {
      float v = ta[base + i] + tb[base + i];
      s += v; s2 = fmaf(v, v, s2);
    }
  }
  for (int off = 32; off; off >>= 1) {
    s += __shfl_down(s, off, 64);
    s2 += __shfl_down(s2, off, 64);
  }
  __shared__ float rs[4], rs2[4];
  const int wid = threadIdx.x >> 6, lane = threadIdx.x & 63;
  if (lane == 0) { rs[wid] = s; rs2[wid] = s2; }
  __syncthreads();
  if (threadIdx.x == 0) {
    float S1 = rs[0] + rs[1] + rs[2] + rs[3];
    float S2 = rs2[0] + rs2[1] + rs2[2] + rs2[3];
    const float cnt = (float)(Bn * N);
    float mean = S1 / cnt;
    float var = S2 / cnt - mean * mean;
    float sc = gamma[c] * rsqrtf(var + 1e-5f);
    ss[2 * c] = sc;
    ss[2 * c + 1] = beta[c] - mean * sc;
  }
}

// ---------------- BN+ReLU (sum of two partials) -> NHWC bf16 padded ----------------
__global__ __launch_bounds__(256) void bn_norm_pad2_kernel(
    const float* __restrict__ ta, const float* __restrict__ tb,
    const float* __restrict__ ss, unsigned short* __restrict__ outp,
    int Wp, int halo) {
  int i = blockIdx.x * 256 + threadIdx.x;
  int n = i & 4095, cg = (i >> 12) & 63, b = i >> 18;
  int c0 = cg * 4;
  ushort4 pk;
  float v0, v1, v2, v3;
  {
    size_t i0 = ((size_t)(b * 256 + c0 + 0)) * N + n;
    size_t i1 = i0 + N, i2 = i1 + N, i3 = i2 + N;
    v0 = fmaxf(fmaf(ta[i0] + tb[i0], ss[2 * (c0 + 0)], ss[2 * (c0 + 0) + 1]), 0.f);
    v1 = fmaxf(fmaf(ta[i1] + tb[i1], ss[2 * (c0 + 1)], ss[2 * (c0 + 1) + 1]), 0.f);
    v2 = fmaxf(fmaf(ta[i2] + tb[i2], ss[2 * (c0 + 2)], ss[2 * (c0 + 2) + 1]), 0.f);
    v3 = fmaxf(fmaf(ta[i3] + tb[i3], ss[2 * (c0 + 3)], ss[2 * (c0 + 3) + 1]), 0.f);
  }
  pk.x = bfc(v0); pk.y = bfc(v1); pk.z = bfc(v2); pk.w = bfc(v3);
  int y = n >> 6, x = n & 63;
  *(ushort4*)(outp + (((size_t)b * Wp + y + halo) * Wp + x + halo) * 256 + c0) = pk;
}

// normalize+ReLU in place (ASPP branch outputs, fp32)
__global__ __launch_bounds__(256) void bn_norm_kernel(
    float* __restrict__ t, const float* __restrict__ ss, int Cmask) {
  int i = blockIdx.x * 256 + threadIdx.x;
  int c = (i >> 12) & Cmask;
  t[i] = fmaxf(fmaf(t[i], ss[2 * c], ss[2 * c + 1]), 0.f);
}

// ---------------- q/k/v 1x1 convs -> bf16 MFMA-layout buffers ----------------
__global__ __launch_bounds__(256) void qkv_kernel(
    const float* __restrict__ br,
    const float* __restrict__ wq, const float* __restrict__ bq,
    const float* __restrict__ wk, const float* __restrict__ bk,
    const float* __restrict__ wv, const float* __restrict__ bvb,
    unsigned short* __restrict__ qTo, unsigned short* __restrict__ kTo,
    unsigned short* __restrict__ vbo) {
  const int bb = blockIdx.z;
  const int p = blockIdx.y >> 2, dg = blockIdx.y & 3;
  const float* w  = p == 0 ? wq : (p == 1 ? wk : wv);
  const float* bi = p == 0 ? bq : (p == 1 ? bk : bvb);
  __shared__ float wl[64 * 16];
  const int d0b = dg * 16;
  for (int i = threadIdx.x; i < 64 * 16; i += 256)
    wl[i] = w[(size_t)(d0b + (i & 15)) * 64 + (i >> 4)];
  __syncthreads();
  const int tn = threadIdx.x & 63, td = threadIdx.x >> 6;
  const int n0 = blockIdx.x * 256 + tn * 4;
  const int d0 = d0b + td * 4;
  const float* inb = br + (size_t)bb * 64 * N;
  float4 acc[4];
#pragma unroll
  for (int j = 0; j < 4; j++) {
    float bvv = bi[d0 + j];
    acc[j] = make_float4(bvv, bvv, bvv, bvv);
  }
  for (int ci = 0; ci < 64; ci++) {
    float4 u = *(const float4*)(inb + (size_t)ci * N + n0);
    float4 wv4 = *(const float4*)(wl + ci * 16 + td * 4);
    fma4(acc[0], wv4.x, u); fma4(acc[1], wv4.y, u);
    fma4(acc[2], wv4.z, u); fma4(acc[3], wv4.w, u);
  }
  const size_t slab = (size_t)bb * N * 64;
  if (p < 2) {
    unsigned short* o = (p == 0 ? qTo : kTo) + slab;
#pragma unroll
    for (int nn = 0; nn < 4; nn++) {
      ushort4 pk;
      pk.x = bfc(((const float*)&acc[0])[nn]);
      pk.y = bfc(((const float*)&acc[1])[nn]);
      pk.z = bfc(((const float*)&acc[2])[nn]);
      pk.w = bfc(((const float*)&acc[3])[nn]);
      *(ushort4*)(o + (size_t)(n0 + nn) * 64 + d0) = pk;
    }
  } else {
    unsigned short* o = vbo + slab;
#pragma unroll
    for (int j = 0; j < 4; j++) {
      ushort4 pk;
      pk.x = bfc(acc[j].x); pk.y = bfc(acc[j].y);
      pk.z = bfc(acc[j].z); pk.w = bfc(acc[j].w);
      *(ushort4*)(o + (size_t)(d0 + j) * N + n0) = pk;
    }
  }
}

// ---------------- posT[n][d] = rel_w[d][h] + rel_h[d][w], bf16 ----------------
__global__ __launch_bounds__(256) void posT_kernel(
    const float* __restrict__ rel_h, const float* __restrict__ rel_w,
    unsigned short* __restrict__ posT) {
  int i = blockIdx.x * 256 + threadIdx.x;  // 65536
  int n = i >> 4, dq = (i & 15) * 4;
  int h = n >> 6, wc = n & 63;
  ushort4 pk;
  pk.x = bfc(rel_w[(dq + 0) * 64 + h] + rel_h[(dq + 0) * 64 + wc]);
  pk.y = bfc(rel_w[(dq + 1) * 64 + h] + rel_h[(dq + 1) * 64 + wc]);
  pk.z = bfc(rel_w[(dq + 2) * 64 + h] + rel_h[(dq + 2) * 64 + wc]);
  pk.w = bfc(rel_w[(dq + 3) * 64 + h] + rel_h[(dq + 3) * 64 + wc]);
  *(ushort4*)(posT + (size_t)n * 64 + dq) = pk;
}

// ---------------- flash v3: LDS-staged A-side (m97 pattern), split-c ----------------
// grid (32 m-tiles of 128, 16 pairs, 4 c-splits); 4 waves x 32 m.
// Per 64-c tile: stage k||q c-rows (16 KB) into LDS dbuf via global_load_lds;
// one barrier per tile; stage(t+1) issued after barrier overlaps compute(t).
__global__ __launch_bounds__(256, 3) void flash3_kernel(
    const unsigned short* __restrict__ qT, const unsigned short* __restrict__ kT,
    const unsigned short* __restrict__ posT, const unsigned short* __restrict__ vb,
    float* __restrict__ o_part, float* __restrict__ ml) {
  const int bb = blockIdx.y, split = blockIdx.z;
  const size_t slab = (size_t)bb * N * 64;
  const unsigned short* qTs = qT + slab;
  const unsigned short* kTs = kT + slab;
  const unsigned short* vbs = vb + slab;
  const int w = threadIdx.x >> 6, lane = threadIdx.x & 63;
  const int ln = lane & 15, quad = lane >> 4;
  const int m0 = blockIdx.x * 128 + w * 32;  // wave's 32 m-rows (2 frags)
  // As[buf][chunk s][c-row 64][32 halfs]; chunk s: s<2 -> kT halfs (s&1)*32, s>=2 -> qT
  __shared__ __align__(16) unsigned short As[2][4][64][32];   // 32 KB
  __shared__ __align__(16) unsigned short pl[4][2][16][72];   // 18 KB per-wave P

  // wave w stages chunk w (4 instrs of 1 KB covering rows j*16..j*16+15)
  const unsigned short* ssrc = (w < 2) ? kTs : qTs;
  const int ksub = (w & 1) * 32 + (lane & 3) * 8;
  const int rsub = lane >> 2;
  auto stage = [&](int c0, int bufi) {
#pragma unroll
    for (int j = 0; j < 4; j++)
      gload_lds16(ssrc + (size_t)(c0 + j * 16 + rsub) * 64 + ksub,
                  &As[bufi][w][j * 16][0]);
  };

  // m-side B fragments: s<2 -> q rows, s>=2 -> pos rows (loaded once)
  bf16x8 bq[4][2];
#pragma unroll
  for (int s = 0; s < 4; s++) {
    const unsigned short* src = (s < 2) ? qTs : posT;
#pragma unroll
    for (int mf = 0; mf < 2; mf++)
      bq[s][mf] = *(const bf16x8*)(src + (size_t)(m0 + mf * 16 + ln) * 64 +
                                   (s & 1) * 32 + quad * 8);
  }

  float m_run[2] = {-3.0e38f, -3.0e38f}, l_run[2] = {0.f, 0.f};
  f32x4 o_acc[4][2];
#pragma unroll
  for (int dt = 0; dt < 4; dt++)
#pragma unroll
    for (int mf = 0; mf < 2; mf++) o_acc[dt][mf] = (f32x4)(0.f);

  const int cbeg = split * 1024;
  stage(cbeg, 0);
  for (int t = 0; t < 16; t++) {
    const int c0 = cbeg + t * 64;
    const int buf = t & 1;
    __syncthreads();               // staging(t) complete; buf (t+1)&1 free
    if (t < 15) stage(c0 + 64, buf ^ 1);  // overlaps compute below
    // ---- S^T from LDS: st[jt][mf][r] = St[c0+jt*16+quad*4+r][m0+mf*16+ln]
    f32x4 st[4][2];
#pragma unroll
    for (int jt = 0; jt < 4; jt++)
#pragma unroll
      for (int mf = 0; mf < 2; mf++) st[jt][mf] = (f32x4)(0.f);
#pragma unroll
    for (int s = 0; s < 4; s++) {
#pragma unroll
      for (int jt = 0; jt < 4; jt++) {
        bf16x8 a = *(const bf16x8*)(&As[buf][s][jt * 16 + ln][quad * 8]);
#pragma unroll
        for (int mf = 0; mf < 2; mf++)
          st[jt][mf] = __builtin_amdgcn_mfma_f32_16x16x32_bf16(a, bq[s][mf], st[jt][mf], 0, 0, 0);
      }
    }
    // ---- online softmax per mf (row state scalar per lane)
#pragma unroll
    for (int mf = 0; mf < 2; mf++) {
      float mx = -3.0e38f;
#pragma unroll
      for (int jt = 0; jt < 4; jt++)
#pragma unroll
        for (int r = 0; r < 4; r++) mx = fmaxf(mx, st[jt][mf][r]);
      mx = fmaxf(mx, __shfl_xor(mx, 16, 64));
      mx = fmaxf(mx, __shfl_xor(mx, 32, 64));
      const float m_new = fmaxf(m_run[mf], mx);
      const float alpha = __expf(m_run[mf] - m_new);
      float psum = 0.f;
#pragma unroll
      for (int jt = 0; jt < 4; jt++) {
        float e0 = __expf(st[jt][mf][0] - m_new);
        float e1 = __expf(st[jt][mf][1] - m_new);
        float e2 = __expf(st[jt][mf][2] - m_new);
        float e3 = __expf(st[jt][mf][3] - m_new);
        psum += (e0 + e1) + (e2 + e3);
        unsigned lo = (unsigned)bfc(e0) | ((unsigned)bfc(e1) << 16);
        unsigned hi = (unsigned)bfc(e2) | ((unsigned)bfc(e3) << 16);
        *(uint2*)(&pl[w][mf][ln][jt * 16 + quad * 4]) = make_uint2(lo, hi);
      }
      psum += __shfl_xor(psum, 16, 64);
      psum += __shfl_xor(psum, 32, 64);
      l_run[mf] = l_run[mf] * alpha + psum;
      m_run[mf] = m_new;
#pragma unroll
      for (int dt = 0; dt < 4; dt++)
#pragma unroll
        for (int r = 0; r < 4; r++) o_acc[dt][mf][r] *= alpha;
    }
    // ---- PV: O[d][m] += V[d][c] * P[c][m]; V register-direct (L1-shared by waves)
#pragma unroll
    for (int tt = 0; tt < 2; tt++) {
      bf16x8 av[4];
#pragma unroll
      for (int dt = 0; dt < 4; dt++)
        av[dt] = *(const bf16x8*)(vbs + (size_t)(dt * 16 + ln) * N + c0 + tt * 32 + quad * 8);
#pragma unroll
      for (int mf = 0; mf < 2; mf++) {
        bf16x8 bp = *(const bf16x8*)(&pl[w][mf][ln][tt * 32 + quad * 8]);
#pragma unroll
        for (int dt = 0; dt < 4; dt++)
          o_acc[dt][mf] = __builtin_amdgcn_mfma_f32_16x16x32_bf16(av[dt], bp, o_acc[dt][mf], 0, 0, 0);
      }
    }
  }
  // ---- epilogue: unnormalized partials
  float* ob = o_part + ((size_t)(split * 16 + bb) * 64) * N;
#pragma unroll
  for (int dt = 0; dt < 4; dt++)
#pragma unroll
    for (int mf = 0; mf < 2; mf++)
#pragma unroll
      for (int r = 0; r < 4; r++) {
        int d = dt * 16 + quad * 4 + r;
        ob[(size_t)d * N + m0 + mf * 16 + ln] = o_acc[dt][mf][r];
      }
  if (quad == 0) {
#pragma unroll
    for (int mf = 0; mf < 2; mf++) {
      int m = m0 + mf * 16 + ln;
      ml[((size_t)(split * 16 + bb) * 2 + 0) * N + m] = m_run[mf];
      ml[((size_t)(split * 16 + bb) * 2 + 1) * N + m] = l_run[mf];
    }
  }
}

// ---------------- combine weights ----------------
__global__ __launch_bounds__(256) void wcomb_kernel(const float* __restrict__ ml,
                                                    float* __restrict__ wcb) {
  int i = blockIdx.x * 256 + threadIdx.x;  // 16*4096
  int m = i & 4095, bb = i >> 12;
  float mv[4], lv[4];
#pragma unroll
  for (int s = 0; s < 4; s++) {
    mv[s] = ml[((size_t)(s * 16 + bb) * 2 + 0) * N + m];
    lv[s] = ml[((size_t)(s * 16 + bb) * 2 + 1) * N + m];
  }
  float M = fmaxf(fmaxf(mv[0], mv[1]), fmaxf(mv[2], mv[3]));
  float wsc[4], denom = 0.f;
#pragma unroll
  for (int s = 0; s < 4; s++) {
    wsc[s] = __expf(mv[s] - M);
    denom = fmaf(wsc[s], lv[s], denom);
  }
  float inv = 1.0f / denom;
#pragma unroll
  for (int s = 0; s < 4; s++)
    wcb[(size_t)(s * 16 + bb) * N + m] = wsc[s] * inv;
}

// ---------------- combine partials -> d_out ----------------
__global__ __launch_bounds__(256) void comb_kernel(const float* __restrict__ o_part,
                                                   const float* __restrict__ wcb,
                                                   float* __restrict__ out) {
  int i = blockIdx.x * 256 + threadIdx.x;
  int m4 = i & 1023, d = (i >> 10) & 63, bb = i >> 16;
  int kbr = bb >> 2, b = bb & 3;
  float4 acc = make_float4(0.f, 0.f, 0.f, 0.f);
#pragma unroll
  for (int s = 0; s < 4; s++) {
    const float4 o = *(const float4*)(o_part + ((size_t)(s * 16 + bb) * 64 + d) * N + m4 * 4);
    const float4 wv = *(const float4*)(wcb + (size_t)(s * 16 + bb) * N + m4 * 4);
    acc.x = fmaf(o.x, wv.x, acc.x); acc.y = fmaf(o.y, wv.y, acc.y);
    acc.z = fmaf(o.z, wv.z, acc.z); acc.w = fmaf(o.w, wv.w, acc.w);
  }
  *(float4*)(out + ((size_t)(b * 256 + kbr * 64 + d)) * N + m4 * 4) = acc;
}

extern "C" void kernel_launch(void* const* d_in, const int* in_sizes, int n_in,
                              void* d_out, int out_size, void* d_ws, size_t ws_size,
                              hipStream_t stream) {
  const float* x      = (const float*)d_in[0];
  const float* dc_w1  = (const float*)d_in[1];
  const float* dc_g1  = (const float*)d_in[3];
  const float* dc_be1 = (const float*)d_in[4];
  const float* dc_w2  = (const float*)d_in[5];
  const float* dc_g2  = (const float*)d_in[7];
  const float* dc_be2 = (const float*)d_in[8];
  const float* aspp_w[4] = {(const float*)d_in[9],  (const float*)d_in[12],
                            (const float*)d_in[15], (const float*)d_in[18]};
  const float* aspp_g[4] = {(const float*)d_in[10], (const float*)d_in[13],
                            (const float*)d_in[16], (const float*)d_in[19]};
  const float* aspp_b[4] = {(const float*)d_in[11], (const float*)d_in[14],
                            (const float*)d_in[17], (const float*)d_in[20]};
  const float* wq = (const float*)d_in[21];
  const float* bq = (const float*)d_in[22];
  const float* wk = (const float*)d_in[23];
  const float* bk = (const float*)d_in[24];
  const float* wv = (const float*)d_in[25];
  const float* bv = (const float*)d_in[26];
  const float* rel_h = (const float*)d_in[27];
  const float* rel_w = (const float*)d_in[28];
  float* out = (float*)d_out;

  float* ws = (float*)d_ws;
  size_t off = 0;
  auto alloc = [&](size_t nf) { float* p = ws + off; off += nf; return p; };
  unsigned short* Pp1 = (unsigned short*)alloc((size_t)4 * 66 * 66 * 128 / 2 + 64);
  unsigned short* Pp2 = (unsigned short*)alloc((size_t)4 * 66 * 66 * 256 / 2 + 64);
  unsigned short* Pp3 = (unsigned short*)alloc((size_t)4 * 82 * 82 * 256 / 2 + 64);
  const size_t HALF = (size_t)4 * 256 * N;
  float* t1   = alloc(2 * HALF);                   // two ci-split partials
  float* br   = alloc((size_t)4 * 4 * 64 * N);
  float* st1  = alloc(512);
  float* st2  = alloc(512);
  float* sta  = alloc(512);
  unsigned short* qT    = (unsigned short*)alloc((size_t)16 * N * 64 / 2);
  unsigned short* kT    = (unsigned short*)alloc((size_t)16 * N * 64 / 2);
  unsigned short* vb    = (unsigned short*)alloc((size_t)16 * N * 64 / 2);
  unsigned short* posT  = (unsigned short*)alloc((size_t)N * 64 / 2);
  unsigned short* wt1   = (unsigned short*)alloc((size_t)9 * 256 * 128 / 2);
  unsigned short* wt2   = (unsigned short*)alloc((size_t)9 * 256 * 256 / 2);
  unsigned short* wtbr  = (unsigned short*)alloc((size_t)4 * 9 * 64 * 256 / 2);
  float* o_part = alloc((size_t)4 * 16 * 64 * N);  // 67 MB
  float* mlb    = alloc((size_t)4 * 16 * 2 * N);
  float* wcb    = alloc((size_t)4 * 16 * N);

  hipMemsetAsync(Pp1, 0, (size_t)4 * 66 * 66 * 128 * 2, stream);
  hipMemsetAsync(Pp2, 0, (size_t)4 * 66 * 66 * 256 * 2, stream);
  hipMemsetAsync(Pp3, 0, (size_t)4 * 82 * 82 * 256 * 2, stream);
  hipMemsetAsync(wtbr, 0, (size_t)4 * 9 * 64 * 256 * 2, stream);

  // weight prep
  wtr_kernel<<<(9 * 256 * 128) / 256, 256, 0, stream>>>(dc_w1, wt1, 256, 128, 9);
  wtr_kernel<<<(9 * 256 * 256) / 256, 256, 0, stream>>>(dc_w2, wt2, 256, 256, 9);
  wtr_kernel<<<(64 * 256) / 256, 256, 0, stream>>>(
      aspp_w[0], wtbr + (size_t)4 * 64 * 256, 64, 256, 1);
  for (int kbr = 1; kbr < 4; kbr++)
    wtr_kernel<<<(9 * 64 * 256) / 256, 256, 0, stream>>>(
        aspp_w[kbr], wtbr + (size_t)kbr * 9 * 64 * 256, 64, 256, 9);

  pool_kernel<<<2048, 256, 0, stream>>>(x, Pp1);

  dcconv_kernel<128><<<dim3(32, 4, 8), 256, 0, stream>>>(Pp1, wt1, t1);
  bn_stats2_kernel<<<256, 256, 0, stream>>>(t1, t1 + HALF, dc_g1, dc_be1, st1, 256);
  bn_norm_pad2_kernel<<<4096, 256, 0, stream>>>(t1, t1 + HALF, st1, Pp2, 66, 1);
  dcconv_kernel<256><<<dim3(32, 4, 8), 256, 0, stream>>>(Pp2, wt2, t1);
  bn_stats2_kernel<<<256, 256, 0, stream>>>(t1, t1 + HALF, dc_g2, dc_be2, st2, 256);
  bn_norm_pad2_kernel<<<4096, 256, 0, stream>>>(t1, t1 + HALF, st2, Pp3, 82, 9);

  branch_kernel<<<dim3(64, 16), 256, 0, stream>>>(Pp3, wtbr, br);
  for (int kbr = 0; kbr < 4; kbr++) {
    bn_stats_kernel<<<64, 256, 0, stream>>>(br + (size_t)kbr * 1048576,
                                            aspp_g[kbr], aspp_b[kbr],
                                            sta + kbr * 128, 64);
    bn_norm_kernel<<<4096, 256, 0, stream>>>(br + (size_t)kbr * 1048576,
                                             sta + kbr * 128, 63);
  }

  qkv_kernel<<<dim3(16, 12, 16), 256, 0, stream>>>(br, wq, bq, wk, bk, wv, bv,
                                                   qT, kT, vb);
  posT_kernel<<<256, 256, 0, stream>>>(rel_h, rel_w, posT);

  flash3_kernel<<<dim3(32, 16, 4), 256, 0, stream>>>(qT, kT, posT, vb, o_part, mlb);
  wcomb_kernel<<<256, 256, 0, stream>>>(mlb, wcb);
  comb_kernel<<<4096, 256, 0, stream>>>(o_part, wcb, out);
}